// Round 1
// baseline (3905.666 us; speedup 1.0000x reference)
//
#include <hip/hip_runtime.h>
#include <math.h>

typedef unsigned short u16;
typedef __attribute__((ext_vector_type(4))) unsigned short us4;
typedef __attribute__((ext_vector_type(4))) float f4;

#define S_LEN   4096
#define D_MODEL 1024
#define N_HEAD  16
#define D_HEAD  64
#define FF_DIM  2048
#define TOKENS  16384  // B*S

__device__ __forceinline__ float bf2f(u16 u) {
  union { float f; unsigned u; } x; x.u = ((unsigned)u) << 16; return x.f;
}
__device__ __forceinline__ u16 f2bf(float f) {
  union { float f; unsigned u; } x; x.f = f;
  return (u16)((x.u + 0x7FFFu + ((x.u >> 16) & 1u)) >> 16);
}

// ---------------------------------------------------------------------------
// RMSNorm: one block per row of 1024. f32 in -> bf16 out.
// ---------------------------------------------------------------------------
__global__ void __launch_bounds__(256)
rmsnorm_k(const float* __restrict__ in, const float* __restrict__ scale,
          u16* __restrict__ out)
{
  const int row = blockIdx.x;
  const int tid = threadIdx.x;
  const f4 v = *(const f4*)(in + (size_t)row * D_MODEL + tid * 4);
  float ss = v[0]*v[0] + v[1]*v[1] + v[2]*v[2] + v[3]*v[3];
#pragma unroll
  for (int off = 32; off > 0; off >>= 1) ss += __shfl_down(ss, off, 64);
  __shared__ float red[4];
  const int wid = tid >> 6, lane = tid & 63;
  if (lane == 0) red[wid] = ss;
  __syncthreads();
  const float tot = red[0] + red[1] + red[2] + red[3];
  const float r = rsqrtf(tot * (1.0f / 1024.0f) + 1e-6f);
  const f4 sc = *(const f4*)(scale + tid * 4);
  us4 o;
  o[0] = f2bf(v[0] * r * sc[0]);
  o[1] = f2bf(v[1] * r * sc[1]);
  o[2] = f2bf(v[2] * r * sc[2]);
  o[3] = f2bf(v[3] * r * sc[3]);
  *(us4*)(out + (size_t)row * D_MODEL + tid * 4) = o;
}

// ---------------------------------------------------------------------------
// GEMM: C[t][n] = sum_k A[t][k] * W[n][k]   (A bf16 [M][K], W f32 [N][K])
// MODE 1: QKV epilogue: bf16 out scattered to [(b*16+h)*64+d][4096] at s
// MODE 2: f32 out = acc + bias + res
// MODE 3: bf16 out = swiglu(acc + bias) = v*sigmoid(v)+v
// Tile 64x64, BK=16, 256 threads, each thread 4x4 outputs (spread-16 mapping).
// ---------------------------------------------------------------------------
template<int MODE>
__global__ void __launch_bounds__(256)
gemm_bt(const u16* __restrict__ A, const float* __restrict__ W,
        const float* __restrict__ bias, const float* res,
        void* Cout, int M, int N, int K)
{
  __shared__ float As[64][20];
  __shared__ float Bs[64][20];
  const int tid  = threadIdx.x;
  const int lrow = tid >> 2;
  const int lk4  = (tid & 3) << 2;
  const int tx = tid & 15, ty = tid >> 4;
  const int m0 = blockIdx.y << 6, n0 = blockIdx.x << 6;

  const u16*   Ap = A + (size_t)(m0 + lrow) * K + lk4;
  const float* Wp = W + (size_t)(n0 + lrow) * K + lk4;

  float acc[4][4] = {};

  for (int k0 = 0; k0 < K; k0 += 16) {
    const us4 av = *(const us4*)(Ap + k0);
    const f4  wv = *(const f4*)(Wp + k0);
    __syncthreads();
    f4 af;
    af[0] = bf2f(av[0]); af[1] = bf2f(av[1]);
    af[2] = bf2f(av[2]); af[3] = bf2f(av[3]);
    *(f4*)&As[lrow][lk4] = af;
    *(f4*)&Bs[lrow][lk4] = wv;
    __syncthreads();
#pragma unroll
    for (int k4 = 0; k4 < 16; k4 += 4) {
      f4 a[4], b[4];
#pragma unroll
      for (int i = 0; i < 4; ++i) a[i] = *(const f4*)&As[ty + 16 * i][k4];
#pragma unroll
      for (int j = 0; j < 4; ++j) b[j] = *(const f4*)&Bs[tx + 16 * j][k4];
#pragma unroll
      for (int kk = 0; kk < 4; ++kk)
#pragma unroll
        for (int i = 0; i < 4; ++i)
#pragma unroll
          for (int j = 0; j < 4; ++j)
            acc[i][j] += a[i][kk] * b[j][kk];
    }
  }

  if (MODE == 1) {
    u16* C = (u16*)Cout;
#pragma unroll
    for (int i = 0; i < 4; ++i) {
      const int t = m0 + ty + 16 * i;
      const int b = t >> 12, s = t & (S_LEN - 1);
#pragma unroll
      for (int j = 0; j < 4; ++j) {
        const int o = n0 + tx + 16 * j;
        const int d = o >> 4, h = o & 15;
        const float v = acc[i][j] + bias[o];
        C[(size_t)(((b << 4) + h) * 64 + d) * S_LEN + s] = f2bf(v);
      }
    }
  } else if (MODE == 2) {
    float* C = (float*)Cout;
#pragma unroll
    for (int i = 0; i < 4; ++i) {
      const int t = m0 + ty + 16 * i;
#pragma unroll
      for (int j = 0; j < 4; ++j) {
        const int n = n0 + tx + 16 * j;
        C[(size_t)t * N + n] = acc[i][j] + bias[n] + res[(size_t)t * N + n];
      }
    }
  } else {  // MODE 3
    u16* C = (u16*)Cout;
#pragma unroll
    for (int i = 0; i < 4; ++i) {
      const int t = m0 + ty + 16 * i;
#pragma unroll
      for (int j = 0; j < 4; ++j) {
        const int n = n0 + tx + 16 * j;
        const float v = acc[i][j] + bias[n];
        const float sig = 1.0f / (1.0f + expf(-v));
        C[(size_t)t * N + n] = f2bf(v * sig + v);
      }
    }
  }
}

// ---------------------------------------------------------------------------
// Scores (split-K): per (b,h): score[d][e] = sum_s qt[d][s]*kt[e][s]
// grid (64, 8): blockIdx.x = bh, blockIdx.y = split p (K range 512 each)
// ---------------------------------------------------------------------------
__global__ void __launch_bounds__(256)
scores_k(const u16* __restrict__ qt, const u16* __restrict__ kt,
         float* __restrict__ spart)
{
  __shared__ float As[64][20];
  __shared__ float Bs[64][20];
  const int bh = blockIdx.x;
  const int p  = blockIdx.y;
  const int tid  = threadIdx.x;
  const int lrow = tid >> 2;
  const int lk4  = (tid & 3) << 2;
  const int tx = tid & 15, ty = tid >> 4;

  const u16* Ap = qt + (size_t)bh * D_HEAD * S_LEN + (size_t)lrow * S_LEN + p * 512 + lk4;
  const u16* Bp = kt + (size_t)bh * D_HEAD * S_LEN + (size_t)lrow * S_LEN + p * 512 + lk4;

  float acc[4][4] = {};
  for (int k0 = 0; k0 < 512; k0 += 16) {
    const us4 av = *(const us4*)(Ap + k0);
    const us4 bv = *(const us4*)(Bp + k0);
    __syncthreads();
    f4 af, bf;
#pragma unroll
    for (int q = 0; q < 4; ++q) { af[q] = bf2f(av[q]); bf[q] = bf2f(bv[q]); }
    *(f4*)&As[lrow][lk4] = af;
    *(f4*)&Bs[lrow][lk4] = bf;
    __syncthreads();
#pragma unroll
    for (int k4 = 0; k4 < 16; k4 += 4) {
      f4 a[4], b[4];
#pragma unroll
      for (int i = 0; i < 4; ++i) a[i] = *(const f4*)&As[ty + 16 * i][k4];
#pragma unroll
      for (int j = 0; j < 4; ++j) b[j] = *(const f4*)&Bs[tx + 16 * j][k4];
#pragma unroll
      for (int kk = 0; kk < 4; ++kk)
#pragma unroll
        for (int i = 0; i < 4; ++i)
#pragma unroll
          for (int j = 0; j < 4; ++j)
            acc[i][j] += a[i][kk] * b[j][kk];
    }
  }
#pragma unroll
  for (int i = 0; i < 4; ++i)
#pragma unroll
    for (int j = 0; j < 4; ++j)
      spart[(((size_t)p * 64 + bh) * 64 + (ty + 16 * i)) * 64 + (tx + 16 * j)] = acc[i][j];
}

// ---------------------------------------------------------------------------
// Softmax over e: att[bh][d][e] = softmax_e( 0.125 * sum_p spart[p][bh][d][e] )
// grid 64 blocks (bh), 64 threads (d).
// ---------------------------------------------------------------------------
__global__ void __launch_bounds__(64)
softmax_k(const float* __restrict__ spart, float* __restrict__ att)
{
  const int bh = blockIdx.x;
  const int d  = threadIdx.x;
  float row[64];
  float mx = -1e30f;
#pragma unroll
  for (int e = 0; e < 64; ++e) {
    float s = 0.0f;
#pragma unroll
    for (int p = 0; p < 8; ++p)
      s += spart[(((size_t)p * 64 + bh) * 64 + d) * 64 + e];
    s *= 0.125f;
    row[e] = s;
    mx = fmaxf(mx, s);
  }
  float den = 0.0f;
#pragma unroll
  for (int e = 0; e < 64; ++e) { row[e] = expf(row[e] - mx); den += row[e]; }
  const float inv = 1.0f / den;
#pragma unroll
  for (int e = 0; e < 64; ++e)
    att[((size_t)bh * 64 + d) * 64 + e] = row[e] * inv;
}

// ---------------------------------------------------------------------------
// PV: a[b,h,d,s] = sum_e att[bh][d][e] * vt[bh][e][s], scattered to
// a_r[b][d*64 + h*4 + (s>>10)][s&1023]  (bf16 out).
// grid (64, 16): bh x s-chunk(256). 256 thr = 64 s-groups(4 s) x 4 d-groups(16 d).
// ---------------------------------------------------------------------------
__global__ void __launch_bounds__(256)
pv_k(const float* __restrict__ att, const u16* __restrict__ vt,
     u16* __restrict__ ar)
{
  __shared__ float attS[64 * 65];
  const int bh = blockIdx.x;
  const int b = bh >> 4, h = bh & 15;
  const int s0 = blockIdx.y << 8;
  const int tid = threadIdx.x;

#pragma unroll
  for (int q = 0; q < 16; ++q) {
    const int idx = q * 256 + tid;
    attS[(idx >> 6) * 65 + (idx & 63)] = att[(size_t)bh * 4096 + idx];
  }
  __syncthreads();

  const int sg = tid & 63;   // s group (4 s each)
  const int dg = tid >> 6;   // d group (16 d each)
  const int s = s0 + (sg << 2);
  const u16* vp = vt + (size_t)bh * D_HEAD * S_LEN + s;

  float acc[16][4] = {};
  for (int e = 0; e < 64; ++e) {
    const us4 vv = *(const us4*)(vp + (size_t)e * S_LEN);
    f4 vf;
    vf[0] = bf2f(vv[0]); vf[1] = bf2f(vv[1]);
    vf[2] = bf2f(vv[2]); vf[3] = bf2f(vv[3]);
#pragma unroll
    for (int dd = 0; dd < 16; ++dd) {
      const float a = attS[(dg * 16 + dd) * 65 + e];
      acc[dd][0] += a * vf[0];
      acc[dd][1] += a * vf[1];
      acc[dd][2] += a * vf[2];
      acc[dd][3] += a * vf[3];
    }
  }

  const int shi = s >> 10;
  const int col = s & 1023;
#pragma unroll
  for (int dd = 0; dd < 16; ++dd) {
    const int d = dg * 16 + dd;
    const int r = (d << 6) + (h << 2) + shi;
    us4 o;
    o[0] = f2bf(acc[dd][0]); o[1] = f2bf(acc[dd][1]);
    o[2] = f2bf(acc[dd][2]); o[3] = f2bf(acc[dd][3]);
    *(us4*)&ar[((size_t)b * 4096 + r) * 1024 + col] = o;
  }
}

// ---------------------------------------------------------------------------
extern "C" void kernel_launch(void* const* d_in, const int* in_sizes, int n_in,
                              void* d_out, int out_size, void* d_ws, size_t ws_size,
                              hipStream_t stream)
{
  const float* x     = (const float*)d_in[0];
  const float* scale = (const float*)d_in[1];
  const float* qw = (const float*)d_in[2];
  const float* qb = (const float*)d_in[3];
  const float* kw = (const float*)d_in[4];
  const float* kb = (const float*)d_in[5];
  const float* vw = (const float*)d_in[6];
  const float* vb = (const float*)d_in[7];
  const float* ow = (const float*)d_in[8];
  const float* ob = (const float*)d_in[9];
  const float* f1w = (const float*)d_in[10];
  const float* f1b = (const float*)d_in[11];
  const float* f2w = (const float*)d_in[12];
  const float* f2b = (const float*)d_in[13];
  float* out = (float*)d_out;

  const size_t TOKD = (size_t)TOKENS * D_MODEL;  // 16.78M elements
  u16* xn = (u16*)d_ws;          // TOKD bf16 (xn, later xn2)
  u16* qt = xn + TOKD;           // TOKD bf16 (qt, later a_r)
  u16* kt = qt + TOKD;           // TOKD bf16 (kt, later h low half)
  u16* vt = kt + TOKD;           // TOKD bf16 (vt, later h high half)
  u16* hbuf = kt;                // TOKENS*FF_DIM bf16 overlays kt+vt
  u16* ar = qt;                  // overlays qt
  float* spart = (float*)(vt + TOKD);        // 8*64*64*64 f32 = 8 MB
  float* att = spart + (size_t)8 * 64 * 64 * 64;  // 64*64*64 f32 = 1 MB

  dim3 blk(256);
  dim3 gN16(D_MODEL / 64, TOKENS / 64);   // (16, 256)
  dim3 gN32(FF_DIM / 64, TOKENS / 64);    // (32, 256)

  // 1. rmsnorm(x) -> xn
  rmsnorm_k<<<TOKENS, blk, 0, stream>>>(x, scale, xn);
  // 2. QKV projections with transpose scatter to [B,H,DH,S]
  gemm_bt<1><<<gN16, blk, 0, stream>>>(xn, qw, qb, nullptr, qt, TOKENS, D_MODEL, D_MODEL);
  gemm_bt<1><<<gN16, blk, 0, stream>>>(xn, kw, kb, nullptr, kt, TOKENS, D_MODEL, D_MODEL);
  gemm_bt<1><<<gN16, blk, 0, stream>>>(xn, vw, vb, nullptr, vt, TOKENS, D_MODEL, D_MODEL);
  // 3. scores split-K partials
  scores_k<<<dim3(64, 8), blk, 0, stream>>>(qt, kt, spart);
  // 4. softmax -> att
  softmax_k<<<64, dim3(64), 0, stream>>>(spart, att);
  // 5. PV + reshape scatter -> a_r
  pv_k<<<dim3(64, 16), blk, 0, stream>>>(att, vt, ar);
  // 6. O projection + bias + residual(x) -> out (f32)
  gemm_bt<2><<<gN16, blk, 0, stream>>>(ar, ow, ob, x, out, TOKENS, D_MODEL, D_MODEL);
  // 7. rmsnorm(out) -> xn (reused as xn2)
  rmsnorm_k<<<TOKENS, blk, 0, stream>>>(out, scale, xn);
  // 8. FFN up + swiglu -> hbuf
  gemm_bt<3><<<gN32, blk, 0, stream>>>(xn, f1w, f1b, nullptr, hbuf, TOKENS, FF_DIM, D_MODEL);
  // 9. FFN down + bias + residual(out) -> out
  gemm_bt<2><<<gN16, blk, 0, stream>>>(hbuf, f2w, f2b, out, out, TOKENS, D_MODEL, FF_DIM);
}

// Round 2
// 590.069 us; speedup vs baseline: 6.6190x; 6.6190x over previous
//
#include <hip/hip_runtime.h>
#include <math.h>

typedef unsigned short u16;
typedef __attribute__((ext_vector_type(4))) unsigned short us4;
typedef __attribute__((ext_vector_type(4))) float f4;
typedef __attribute__((ext_vector_type(8))) short bf16x8;
typedef __attribute__((ext_vector_type(4))) float f32x4;

#define S_LEN   4096
#define D_MODEL 1024
#define N_HEAD  16
#define D_HEAD  64
#define FF_DIM  2048
#define TOKENS  16384  // B*S

__device__ __forceinline__ float bf2f(u16 u) {
  union { float f; unsigned u; } x; x.u = ((unsigned)u) << 16; return x.f;
}
__device__ __forceinline__ u16 f2bf(float f) {
  union { float f; unsigned u; } x; x.f = f;
  return (u16)((x.u + 0x7FFFu + ((x.u >> 16) & 1u)) >> 16);
}

__device__ __forceinline__ void gll16(const void* g, void* l) {
  __builtin_amdgcn_global_load_lds(
      (const __attribute__((address_space(1))) void*)g,
      (__attribute__((address_space(3))) void*)l, 16, 0, 0);
}

// ---------------------------------------------------------------------------
// f32 -> bf16 weight conversion (4 elems/thread)
// ---------------------------------------------------------------------------
__global__ void __launch_bounds__(256)
cvt_k(const float* __restrict__ in, u16* __restrict__ out)
{
  const int i = blockIdx.x * 256 + threadIdx.x;
  const f4 v = *(const f4*)(in + (size_t)i * 4);
  us4 o;
  o[0] = f2bf(v[0]); o[1] = f2bf(v[1]); o[2] = f2bf(v[2]); o[3] = f2bf(v[3]);
  *(us4*)(out + (size_t)i * 4) = o;
}

// ---------------------------------------------------------------------------
// RMSNorm: one block per row of 1024. f32 in -> bf16 out.
// ---------------------------------------------------------------------------
__global__ void __launch_bounds__(256)
rmsnorm_k(const float* __restrict__ in, const float* __restrict__ scale,
          u16* __restrict__ out)
{
  const int row = blockIdx.x;
  const int tid = threadIdx.x;
  const f4 v = *(const f4*)(in + (size_t)row * D_MODEL + tid * 4);
  float ss = v[0]*v[0] + v[1]*v[1] + v[2]*v[2] + v[3]*v[3];
#pragma unroll
  for (int off = 32; off > 0; off >>= 1) ss += __shfl_down(ss, off, 64);
  __shared__ float red[4];
  const int wid = tid >> 6, lane = tid & 63;
  if (lane == 0) red[wid] = ss;
  __syncthreads();
  const float tot = red[0] + red[1] + red[2] + red[3];
  const float r = rsqrtf(tot * (1.0f / 1024.0f) + 1e-6f);
  const f4 sc = *(const f4*)(scale + tid * 4);
  us4 o;
  o[0] = f2bf(v[0] * r * sc[0]);
  o[1] = f2bf(v[1] * r * sc[1]);
  o[2] = f2bf(v[2] * r * sc[2]);
  o[3] = f2bf(v[3] * r * sc[3]);
  *(us4*)(out + (size_t)row * D_MODEL + tid * 4) = o;
}

// ---------------------------------------------------------------------------
// MFMA K-loop (m97 structure): 128x128 tile, BK=32, 4 waves, single-buffer LDS
// staged with global_load_lds width=16, 2 barriers per K-step.
// Wave w -> 64x64 sub-tile at (wr*64, wc*64); 4x4 frags of 16x16x32 bf16.
// ---------------------------------------------------------------------------
__device__ __forceinline__ void kloop(const u16* __restrict__ gA, const u16* __restrict__ gB,
                                      u16* As, u16* Bs, int K, int w, int wr, int wc,
                                      int fr, int fq, f32x4 acc[4][4])
{
  u16* lA0 = As + w * 512;         // wave-uniform 1KB chunk bases
  u16* lA1 = lA0 + 2048;
  u16* lB0 = Bs + w * 512;
  u16* lB1 = lB0 + 2048;
  const size_t rowK = (size_t)64 * K;
  for (int k0 = 0; k0 < K; k0 += 32) {
    __syncthreads();               // all waves done reading LDS
    gll16(gA + k0,        lA0);
    gll16(gA + k0 + rowK, lA1);
    gll16(gB + k0,        lB0);
    gll16(gB + k0 + rowK, lB1);
    __syncthreads();               // vmcnt(0) drain + barrier
    bf16x8 a[4], b[4];
#pragma unroll
    for (int m = 0; m < 4; ++m)
      a[m] = *(const bf16x8*)(As + (wr*64 + m*16 + fr) * 32 + fq*8);
#pragma unroll
    for (int n = 0; n < 4; ++n)
      b[n] = *(const bf16x8*)(Bs + (wc*64 + n*16 + fr) * 32 + fq*8);
#pragma unroll
    for (int m = 0; m < 4; ++m)
#pragma unroll
      for (int n = 0; n < 4; ++n)
        acc[m][n] = __builtin_amdgcn_mfma_f32_16x16x32_bf16(a[m], b[n], acc[m][n], 0, 0, 0);
  }
}

// ---------------------------------------------------------------------------
// QKV fused (blockIdx.z selects q/k/v). C = A(bf16) * W(bf16)^T + bias,
// output bf16 scattered to [(b*16+h)*64+d][4096] via LDS transpose re-stage.
// ---------------------------------------------------------------------------
__global__ void __launch_bounds__(256)
mgemm_qkv(const u16* __restrict__ A,
          const u16* __restrict__ Wq, const u16* __restrict__ Wk, const u16* __restrict__ Wv,
          const float* __restrict__ bq, const float* __restrict__ bk, const float* __restrict__ bv,
          u16* __restrict__ Cq, u16* __restrict__ Ck, u16* __restrict__ Cv)
{
  __shared__ u16 As[128 * 32];
  __shared__ u16 Bs[128 * 32];
  __shared__ u16 Cs[128 * 132];    // [c(o-local)][r(token-local)], pad 132
  const int z = blockIdx.z;
  const u16*   W    = z == 0 ? Wq : (z == 1 ? Wk : Wv);
  const float* bias = z == 0 ? bq : (z == 1 ? bk : bv);
  u16*         Cout = z == 0 ? Cq : (z == 1 ? Ck : Cv);
  const int K = D_MODEL;
  const int tid = threadIdx.x, w = tid >> 6, l = tid & 63;
  const int m0 = blockIdx.y << 7, n0 = blockIdx.x << 7;
  const int srow = w * 16 + (l >> 2), sk = (l & 3) * 8;
  const u16* gA = A + (size_t)(m0 + srow) * K + sk;
  const u16* gB = W + (size_t)(n0 + srow) * K + sk;
  const int wr = w >> 1, wc = w & 1, fr = l & 15, fq = l >> 4;
  f32x4 acc[4][4] = {};
  kloop(gA, gB, As, Bs, K, w, wr, wc, fr, fq, acc);

  const int bb = m0 >> 12, scol0 = m0 & (S_LEN - 1);
#pragma unroll
  for (int m = 0; m < 4; ++m)
#pragma unroll
    for (int n = 0; n < 4; ++n) {
      const int c  = wc * 64 + n * 16 + fr;
      const int r0 = wr * 64 + m * 16 + fq * 4;
      us4 pk;
#pragma unroll
      for (int j = 0; j < 4; ++j) pk[j] = f2bf(acc[m][n][j] + bias[n0 + c]);
      *(us4*)&Cs[c * 132 + r0] = pk;
    }
  __syncthreads();
#pragma unroll
  for (int p = 0; p < 16; ++p) {
    const int c = p * 8 + (tid >> 5), sg = tid & 31;
    const us4 v = *(const us4*)&Cs[c * 132 + sg * 4];
    const int o = n0 + c, d = o >> 4, h = o & 15;
    u16* dst = Cout + ((size_t)((bb << 10) + (h << 6) + d)) * S_LEN + scol0 + sg * 4;
    *(us4*)dst = v;
  }
}

// ---------------------------------------------------------------------------
// Generic MFMA GEMM. MODE 2: f32 out = acc+bias+res (row-major [M][N]).
//                    MODE 3: bf16 out = swiglu(acc+bias) (row-major).
// ---------------------------------------------------------------------------
template<int MODE>
__global__ void __launch_bounds__(256)
mgemm(const u16* __restrict__ A, const u16* __restrict__ W,
      const float* __restrict__ bias, const float* __restrict__ res,
      void* __restrict__ Cout, int N, int K)
{
  __shared__ u16 As[128 * 32];
  __shared__ u16 Bs[128 * 32];
  const int tid = threadIdx.x, w = tid >> 6, l = tid & 63;
  const int m0 = blockIdx.y << 7, n0 = blockIdx.x << 7;
  const int srow = w * 16 + (l >> 2), sk = (l & 3) * 8;
  const u16* gA = A + (size_t)(m0 + srow) * K + sk;
  const u16* gB = W + (size_t)(n0 + srow) * K + sk;
  const int wr = w >> 1, wc = w & 1, fr = l & 15, fq = l >> 4;
  f32x4 acc[4][4] = {};
  kloop(gA, gB, As, Bs, K, w, wr, wc, fr, fq, acc);

#pragma unroll
  for (int m = 0; m < 4; ++m)
#pragma unroll
    for (int n = 0; n < 4; ++n) {
      const int c = n0 + wc * 64 + n * 16 + fr;
      if constexpr (MODE == 2) {
        float* C = (float*)Cout;
#pragma unroll
        for (int j = 0; j < 4; ++j) {
          const int r = m0 + wr * 64 + m * 16 + fq * 4 + j;
          C[(size_t)r * N + c] = acc[m][n][j] + bias[c] + res[(size_t)r * N + c];
        }
      } else {
        u16* C = (u16*)Cout;
#pragma unroll
        for (int j = 0; j < 4; ++j) {
          const int r = m0 + wr * 64 + m * 16 + fq * 4 + j;
          const float v = acc[m][n][j] + bias[c];
          const float sig = 1.0f / (1.0f + expf(-v));
          C[(size_t)r * N + c] = f2bf(v * sig + v);
        }
      }
    }
}

// ---------------------------------------------------------------------------
// Scores (split-K): per (b,h): score[d][e] = sum_s qt[d][s]*kt[e][s]
// ---------------------------------------------------------------------------
__global__ void __launch_bounds__(256)
scores_k(const u16* __restrict__ qt, const u16* __restrict__ kt,
         float* __restrict__ spart)
{
  __shared__ float As[64][20];
  __shared__ float Bs[64][20];
  const int bh = blockIdx.x;
  const int p  = blockIdx.y;
  const int tid  = threadIdx.x;
  const int lrow = tid >> 2;
  const int lk4  = (tid & 3) << 2;
  const int tx = tid & 15, ty = tid >> 4;

  const u16* Ap = qt + (size_t)bh * D_HEAD * S_LEN + (size_t)lrow * S_LEN + p * 512 + lk4;
  const u16* Bp = kt + (size_t)bh * D_HEAD * S_LEN + (size_t)lrow * S_LEN + p * 512 + lk4;

  float acc[4][4] = {};
  for (int k0 = 0; k0 < 512; k0 += 16) {
    const us4 av = *(const us4*)(Ap + k0);
    const us4 bv = *(const us4*)(Bp + k0);
    __syncthreads();
    f4 af, bf;
#pragma unroll
    for (int q = 0; q < 4; ++q) { af[q] = bf2f(av[q]); bf[q] = bf2f(bv[q]); }
    *(f4*)&As[lrow][lk4] = af;
    *(f4*)&Bs[lrow][lk4] = bf;
    __syncthreads();
#pragma unroll
    for (int k4 = 0; k4 < 16; k4 += 4) {
      f4 a[4], b[4];
#pragma unroll
      for (int i = 0; i < 4; ++i) a[i] = *(const f4*)&As[ty + 16 * i][k4];
#pragma unroll
      for (int j = 0; j < 4; ++j) b[j] = *(const f4*)&Bs[tx + 16 * j][k4];
#pragma unroll
      for (int kk = 0; kk < 4; ++kk)
#pragma unroll
        for (int i = 0; i < 4; ++i)
#pragma unroll
          for (int j = 0; j < 4; ++j)
            acc[i][j] += a[i][kk] * b[j][kk];
    }
  }
#pragma unroll
  for (int i = 0; i < 4; ++i)
#pragma unroll
    for (int j = 0; j < 4; ++j)
      spart[(((size_t)p * 64 + bh) * 64 + (ty + 16 * i)) * 64 + (tx + 16 * j)] = acc[i][j];
}

// ---------------------------------------------------------------------------
// Softmax over e
// ---------------------------------------------------------------------------
__global__ void __launch_bounds__(64)
softmax_k(const float* __restrict__ spart, float* __restrict__ att)
{
  const int bh = blockIdx.x;
  const int d  = threadIdx.x;
  float row[64];
  float mx = -1e30f;
#pragma unroll
  for (int e = 0; e < 64; ++e) {
    float s = 0.0f;
#pragma unroll
    for (int p = 0; p < 8; ++p)
      s += spart[(((size_t)p * 64 + bh) * 64 + d) * 64 + e];
    s *= 0.125f;
    row[e] = s;
    mx = fmaxf(mx, s);
  }
  float den = 0.0f;
#pragma unroll
  for (int e = 0; e < 64; ++e) { row[e] = expf(row[e] - mx); den += row[e]; }
  const float inv = 1.0f / den;
#pragma unroll
  for (int e = 0; e < 64; ++e)
    att[((size_t)bh * 64 + d) * 64 + e] = row[e] * inv;
}

// ---------------------------------------------------------------------------
// PV + reshape scatter
// ---------------------------------------------------------------------------
__global__ void __launch_bounds__(256)
pv_k(const float* __restrict__ att, const u16* __restrict__ vt,
     u16* __restrict__ ar)
{
  __shared__ float attS[64 * 65];
  const int bh = blockIdx.x;
  const int b = bh >> 4, h = bh & 15;
  const int s0 = blockIdx.y << 8;
  const int tid = threadIdx.x;

#pragma unroll
  for (int q = 0; q < 16; ++q) {
    const int idx = q * 256 + tid;
    attS[(idx >> 6) * 65 + (idx & 63)] = att[(size_t)bh * 4096 + idx];
  }
  __syncthreads();

  const int sg = tid & 63;
  const int dg = tid >> 6;
  const int s = s0 + (sg << 2);
  const u16* vp = vt + (size_t)bh * D_HEAD * S_LEN + s;

  float acc[16][4] = {};
  for (int e = 0; e < 64; ++e) {
    const us4 vv = *(const us4*)(vp + (size_t)e * S_LEN);
    f4 vf;
    vf[0] = bf2f(vv[0]); vf[1] = bf2f(vv[1]);
    vf[2] = bf2f(vv[2]); vf[3] = bf2f(vv[3]);
#pragma unroll
    for (int dd = 0; dd < 16; ++dd) {
      const float a = attS[(dg * 16 + dd) * 65 + e];
      acc[dd][0] += a * vf[0];
      acc[dd][1] += a * vf[1];
      acc[dd][2] += a * vf[2];
      acc[dd][3] += a * vf[3];
    }
  }

  const int shi = s >> 10;
  const int col = s & 1023;
#pragma unroll
  for (int dd = 0; dd < 16; ++dd) {
    const int d = dg * 16 + dd;
    const int r = (d << 6) + (h << 2) + shi;
    us4 o;
    o[0] = f2bf(acc[dd][0]); o[1] = f2bf(acc[dd][1]);
    o[2] = f2bf(acc[dd][2]); o[3] = f2bf(acc[dd][3]);
    *(us4*)&ar[((size_t)b * 4096 + r) * 1024 + col] = o;
  }
}

// ---------------------------------------------------------------------------
extern "C" void kernel_launch(void* const* d_in, const int* in_sizes, int n_in,
                              void* d_out, int out_size, void* d_ws, size_t ws_size,
                              hipStream_t stream)
{
  const float* x     = (const float*)d_in[0];
  const float* scale = (const float*)d_in[1];
  const float* qw = (const float*)d_in[2];
  const float* qb = (const float*)d_in[3];
  const float* kw = (const float*)d_in[4];
  const float* kb = (const float*)d_in[5];
  const float* vw = (const float*)d_in[6];
  const float* vb = (const float*)d_in[7];
  const float* ow = (const float*)d_in[8];
  const float* ob = (const float*)d_in[9];
  const float* f1w = (const float*)d_in[10];
  const float* f1b = (const float*)d_in[11];
  const float* f2w = (const float*)d_in[12];
  const float* f2b = (const float*)d_in[13];
  float* out = (float*)d_out;

  const size_t TOKD = (size_t)TOKENS * D_MODEL;   // 16.78M elems
  const size_t WSZ1 = (size_t)D_MODEL * D_MODEL;  // 1M
  const size_t WSZ2 = (size_t)FF_DIM * D_MODEL;   // 2M
  u16* xn = (u16*)d_ws;
  u16* qt = xn + TOKD;
  u16* kt = qt + TOKD;
  u16* vt = kt + TOKD;
  u16* wq = vt + TOKD;        // bf16 weights: 8M elems total
  u16* wk = wq + WSZ1;
  u16* wv = wk + WSZ1;
  u16* wo = wv + WSZ1;
  u16* w1 = wo + WSZ1;
  u16* w2 = w1 + WSZ2;
  u16* hbuf = kt;             // overlays kt+vt (dead after attention)
  u16* ar = qt;               // overlays qt (dead after scores)
  float* spart = (float*)xn;  // overlays xn (dead during attention core)
  float* att = spart + (size_t)8 * 64 * 64 * 64;

  dim3 blk(256);

  // 0. weights f32 -> bf16
  cvt_k<<<WSZ1 / 1024, blk, 0, stream>>>(qw, wq);
  cvt_k<<<WSZ1 / 1024, blk, 0, stream>>>(kw, wk);
  cvt_k<<<WSZ1 / 1024, blk, 0, stream>>>(vw, wv);
  cvt_k<<<WSZ1 / 1024, blk, 0, stream>>>(ow, wo);
  cvt_k<<<WSZ2 / 1024, blk, 0, stream>>>(f1w, w1);
  cvt_k<<<WSZ2 / 1024, blk, 0, stream>>>(f2w, w2);

  // 1. rmsnorm(x) -> xn
  rmsnorm_k<<<TOKENS, blk, 0, stream>>>(x, scale, xn);
  // 2. QKV projections (fused z-grid) with transpose scatter to [B,H,DH,S]
  mgemm_qkv<<<dim3(D_MODEL / 128, TOKENS / 128, 3), blk, 0, stream>>>(
      xn, wq, wk, wv, qb, kb, vb, qt, kt, vt);
  // 3. scores split-K partials
  scores_k<<<dim3(64, 8), blk, 0, stream>>>(qt, kt, spart);
  // 4. softmax -> att
  softmax_k<<<64, dim3(64), 0, stream>>>(spart, att);
  // 5. PV + reshape scatter -> a_r
  pv_k<<<dim3(64, 16), blk, 0, stream>>>(att, vt, ar);
  // 6. O projection + bias + residual(x) -> out (f32)
  mgemm<2><<<dim3(D_MODEL / 128, TOKENS / 128), blk, 0, stream>>>(
      ar, wo, ob, x, out, D_MODEL, D_MODEL);
  // 7. rmsnorm(out) -> xn
  rmsnorm_k<<<TOKENS, blk, 0, stream>>>(out, scale, xn);
  // 8. FFN up + swiglu -> hbuf (bf16 [T][2048])
  mgemm<3><<<dim3(FF_DIM / 128, TOKENS / 128), blk, 0, stream>>>(
      xn, w1, f1b, nullptr, hbuf, FF_DIM, D_MODEL);
  // 9. FFN down + bias + residual(out) -> out
  mgemm<2><<<dim3(D_MODEL / 128, TOKENS / 128), blk, 0, stream>>>(
      hbuf, w2, f2b, out, out, D_MODEL, FF_DIM);
}

// Round 3
// 572.114 us; speedup vs baseline: 6.8267x; 1.0314x over previous
//
#include <hip/hip_runtime.h>
#include <math.h>

typedef unsigned short u16;
typedef __attribute__((ext_vector_type(4))) unsigned short us4;
typedef __attribute__((ext_vector_type(8))) unsigned short us8;
typedef __attribute__((ext_vector_type(4))) float f4;
typedef __attribute__((ext_vector_type(8))) short bf16x8;
typedef __attribute__((ext_vector_type(4))) float f32x4;

#define S_LEN   4096
#define D_MODEL 1024
#define N_HEAD  16
#define D_HEAD  64
#define FF_DIM  2048
#define TOKENS  16384  // B*S

__device__ __forceinline__ float bf2f(u16 u) {
  union { float f; unsigned u; } x; x.u = ((unsigned)u) << 16; return x.f;
}
__device__ __forceinline__ u16 f2bf(float f) {
  union { float f; unsigned u; } x; x.f = f;
  return (u16)((x.u + 0x7FFFu + ((x.u >> 16) & 1u)) >> 16);
}

__device__ __forceinline__ void gll16(const void* g, void* l) {
  __builtin_amdgcn_global_load_lds(
      (const __attribute__((address_space(1))) void*)g,
      (__attribute__((address_space(3))) void*)l, 16, 0, 0);
}

// ---------------------------------------------------------------------------
// Fused f32 -> bf16 weight conversion for all 6 weight matrices.
// 1024 elems per block.
// ---------------------------------------------------------------------------
__global__ void __launch_bounds__(256)
cvt6_k(const float* __restrict__ qw, const float* __restrict__ kw,
       const float* __restrict__ vw, const float* __restrict__ ow,
       const float* __restrict__ f1w, const float* __restrict__ f2w,
       u16* __restrict__ wq, u16* __restrict__ wk, u16* __restrict__ wv,
       u16* __restrict__ wo, u16* __restrict__ w1, u16* __restrict__ w2)
{
  const int id = blockIdx.x;
  const float* src; u16* dst; int base;
  if      (id < 1024) { src = qw;  dst = wq; base = 0; }
  else if (id < 2048) { src = kw;  dst = wk; base = 1024; }
  else if (id < 3072) { src = vw;  dst = wv; base = 2048; }
  else if (id < 4096) { src = ow;  dst = wo; base = 3072; }
  else if (id < 6144) { src = f1w; dst = w1; base = 4096; }
  else                { src = f2w; dst = w2; base = 6144; }
  const size_t i = ((size_t)(id - base) * 256 + threadIdx.x) * 4;
  const f4 v = *(const f4*)(src + i);
  us4 o;
  o[0] = f2bf(v[0]); o[1] = f2bf(v[1]); o[2] = f2bf(v[2]); o[3] = f2bf(v[3]);
  *(us4*)(dst + i) = o;
}

// ---------------------------------------------------------------------------
// RMSNorm: one block per row of 1024. f32 in -> bf16 out.
// ---------------------------------------------------------------------------
__global__ void __launch_bounds__(256)
rmsnorm_k(const float* __restrict__ in, const float* __restrict__ scale,
          u16* __restrict__ out)
{
  const int row = blockIdx.x;
  const int tid = threadIdx.x;
  const f4 v = *(const f4*)(in + (size_t)row * D_MODEL + tid * 4);
  float ss = v[0]*v[0] + v[1]*v[1] + v[2]*v[2] + v[3]*v[3];
#pragma unroll
  for (int off = 32; off > 0; off >>= 1) ss += __shfl_down(ss, off, 64);
  __shared__ float red[4];
  const int wid = tid >> 6, lane = tid & 63;
  if (lane == 0) red[wid] = ss;
  __syncthreads();
  const float tot = red[0] + red[1] + red[2] + red[3];
  const float r = rsqrtf(tot * (1.0f / 1024.0f) + 1e-6f);
  const f4 sc = *(const f4*)(scale + tid * 4);
  us4 o;
  o[0] = f2bf(v[0] * r * sc[0]);
  o[1] = f2bf(v[1] * r * sc[1]);
  o[2] = f2bf(v[2] * r * sc[2]);
  o[3] = f2bf(v[3] * r * sc[3]);
  *(us4*)(out + (size_t)row * D_MODEL + tid * 4) = o;
}

// ---------------------------------------------------------------------------
// MFMA K-loop (m97 structure): 128x128 tile, BK=32, 4 waves.
// ---------------------------------------------------------------------------
__device__ __forceinline__ void kloop(const u16* __restrict__ gA, const u16* __restrict__ gB,
                                      u16* As, u16* Bs, int K, int w, int wr, int wc,
                                      int fr, int fq, f32x4 acc[4][4])
{
  u16* lA0 = As + w * 512;
  u16* lA1 = lA0 + 2048;
  u16* lB0 = Bs + w * 512;
  u16* lB1 = lB0 + 2048;
  const size_t rowK = (size_t)64 * K;
  for (int k0 = 0; k0 < K; k0 += 32) {
    __syncthreads();
    gll16(gA + k0,        lA0);
    gll16(gA + k0 + rowK, lA1);
    gll16(gB + k0,        lB0);
    gll16(gB + k0 + rowK, lB1);
    __syncthreads();
    bf16x8 a[4], b[4];
#pragma unroll
    for (int m = 0; m < 4; ++m)
      a[m] = *(const bf16x8*)(As + (wr*64 + m*16 + fr) * 32 + fq*8);
#pragma unroll
    for (int n = 0; n < 4; ++n)
      b[n] = *(const bf16x8*)(Bs + (wc*64 + n*16 + fr) * 32 + fq*8);
#pragma unroll
    for (int m = 0; m < 4; ++m)
#pragma unroll
      for (int n = 0; n < 4; ++n)
        acc[m][n] = __builtin_amdgcn_mfma_f32_16x16x32_bf16(a[m], b[n], acc[m][n], 0, 0, 0);
  }
}

// ---------------------------------------------------------------------------
// QKV fused (blockIdx.z selects q/k/v).
// z=0,1: bf16 out scattered to qt/kt [bh][d][4096] via LDS transpose re-stage.
// z=2:   bf16 out scattered to v2 [bh][s][64] (d-contiguous 16B chunks).
// Grid: (TOKENS/128, N/128, 3) -- m on x so same-A-panel blocks share an XCD.
// ---------------------------------------------------------------------------
__global__ void __launch_bounds__(256)
mgemm_qkv(const u16* __restrict__ A,
          const u16* __restrict__ Wq, const u16* __restrict__ Wk, const u16* __restrict__ Wv,
          const float* __restrict__ bq, const float* __restrict__ bk, const float* __restrict__ bv,
          u16* __restrict__ Cq, u16* __restrict__ Ck, u16* __restrict__ Cv)
{
  __shared__ u16 As[128 * 32];
  __shared__ u16 Bs[128 * 32];
  __shared__ u16 Cs[128 * 132];
  const int z = blockIdx.z;
  const u16*   W    = z == 0 ? Wq : (z == 1 ? Wk : Wv);
  const float* bias = z == 0 ? bq : (z == 1 ? bk : bv);
  const int K = D_MODEL;
  const int tid = threadIdx.x, w = tid >> 6, l = tid & 63;
  const int m0 = blockIdx.x << 7, n0 = blockIdx.y << 7;
  const int srow = w * 16 + (l >> 2), sk = (l & 3) * 8;
  const u16* gA = A + (size_t)(m0 + srow) * K + sk;
  const u16* gB = W + (size_t)(n0 + srow) * K + sk;
  const int wr = w >> 1, wc = w & 1, fr = l & 15, fq = l >> 4;
  f32x4 acc[4][4] = {};
  kloop(gA, gB, As, Bs, K, w, wr, wc, fr, fq, acc);

#pragma unroll
  for (int m = 0; m < 4; ++m)
#pragma unroll
    for (int n = 0; n < 4; ++n) {
      const int c  = wc * 64 + n * 16 + fr;
      const int r0 = wr * 64 + m * 16 + fq * 4;
      us4 pk;
#pragma unroll
      for (int j = 0; j < 4; ++j) pk[j] = f2bf(acc[m][n][j] + bias[n0 + c]);
      *(us4*)&Cs[c * 132 + r0] = pk;
    }
  __syncthreads();

  const int bb = m0 >> 12, s0l = m0 & (S_LEN - 1);
  if (z < 2) {
    u16* Cout = z == 0 ? Cq : Ck;
#pragma unroll
    for (int p = 0; p < 16; ++p) {
      const int c = p * 8 + (tid >> 5), sg = tid & 31;
      const us4 v = *(const us4*)&Cs[c * 132 + sg * 4];
      const int o = n0 + c, d = o >> 4, h = o & 15;
      u16* dst = Cout + ((size_t)((bb << 10) + (h << 6) + d)) * S_LEN + s0l + sg * 4;
      *(us4*)dst = v;
    }
  } else {
    // v2[((b*16+h)*4096 + s)*64 + d]
    const int d0 = n0 >> 4;
#pragma unroll
    for (int p = 0; p < 8; ++p) {
      const int chunk = p * 256 + tid;     // 2048 chunks = 16 h x 128 r
      const int h = chunk >> 7, r = chunk & 127;
      us8 o;
#pragma unroll
      for (int dl = 0; dl < 8; ++dl) o[dl] = Cs[(dl * 16 + h) * 132 + r];
      u16* dst = Cv + ((size_t)(bb * 16 + h) * S_LEN + s0l + r) * 64 + d0;
      *(us8*)dst = o;
    }
  }
}

// ---------------------------------------------------------------------------
// Generic MFMA GEMM. MODE 2: f32 out = acc+bias+res. MODE 3: bf16 swiglu out.
// Grid: (M/128, N/128) -- m on x for XCD panel sharing.
// ---------------------------------------------------------------------------
template<int MODE>
__global__ void __launch_bounds__(256)
mgemm(const u16* __restrict__ A, const u16* __restrict__ W,
      const float* __restrict__ bias, const float* __restrict__ res,
      void* __restrict__ Cout, int N, int K)
{
  __shared__ u16 As[128 * 32];
  __shared__ u16 Bs[128 * 32];
  const int tid = threadIdx.x, w = tid >> 6, l = tid & 63;
  const int m0 = blockIdx.x << 7, n0 = blockIdx.y << 7;
  const int srow = w * 16 + (l >> 2), sk = (l & 3) * 8;
  const u16* gA = A + (size_t)(m0 + srow) * K + sk;
  const u16* gB = W + (size_t)(n0 + srow) * K + sk;
  const int wr = w >> 1, wc = w & 1, fr = l & 15, fq = l >> 4;
  f32x4 acc[4][4] = {};
  kloop(gA, gB, As, Bs, K, w, wr, wc, fr, fq, acc);

#pragma unroll
  for (int m = 0; m < 4; ++m)
#pragma unroll
    for (int n = 0; n < 4; ++n) {
      const int c = n0 + wc * 64 + n * 16 + fr;
      if constexpr (MODE == 2) {
        float* C = (float*)Cout;
#pragma unroll
        for (int j = 0; j < 4; ++j) {
          const int r = m0 + wr * 64 + m * 16 + fq * 4 + j;
          C[(size_t)r * N + c] = acc[m][n][j] + bias[c] + res[(size_t)r * N + c];
        }
      } else {
        u16* C = (u16*)Cout;
#pragma unroll
        for (int j = 0; j < 4; ++j) {
          const int r = m0 + wr * 64 + m * 16 + fq * 4 + j;
          const float v = acc[m][n][j] + bias[c];
          const float sig = 1.0f / (1.0f + expf(-v));
          C[(size_t)r * N + c] = f2bf(v * sig + v);
        }
      }
    }
}

// ---------------------------------------------------------------------------
// Fused scores + softmax per (b,h). One block per bh, 4 waves.
// Wave w covers s in [w*1024, w*1024+1024). Frags loaded direct from global.
// score[d][e] = sum_s Q[d][s]*K[e][s]; P = softmax_e(score/8) -> bf16 [64][64]
// ---------------------------------------------------------------------------
__global__ void __launch_bounds__(256)
att_sm_k(const u16* __restrict__ qt, const u16* __restrict__ kt,
         u16* __restrict__ P)
{
  __shared__ float red[4][64][64];   // [wave][e][d]
  const int bh = blockIdx.x;
  const int tid = threadIdx.x, w = tid >> 6, l = tid & 63;
  const int fr = l & 15, fq = l >> 4;
  const u16* Qb = qt + (size_t)bh * D_HEAD * S_LEN;
  const u16* Kb = kt + (size_t)bh * D_HEAD * S_LEN;
  f32x4 acc[4][4] = {};
  const int sb = w * 1024 + fq * 8;
  for (int ks = 0; ks < 32; ++ks) {
    const int s0 = sb + ks * 32;
    bf16x8 a[4], b[4];
#pragma unroll
    for (int m = 0; m < 4; ++m)
      a[m] = *(const bf16x8*)(Qb + (size_t)(m*16 + fr) * S_LEN + s0);
#pragma unroll
    for (int n = 0; n < 4; ++n)
      b[n] = *(const bf16x8*)(Kb + (size_t)(n*16 + fr) * S_LEN + s0);
#pragma unroll
    for (int m = 0; m < 4; ++m)
#pragma unroll
      for (int n = 0; n < 4; ++n)
        acc[m][n] = __builtin_amdgcn_mfma_f32_16x16x32_bf16(a[m], b[n], acc[m][n], 0, 0, 0);
  }
#pragma unroll
  for (int m = 0; m < 4; ++m)
#pragma unroll
    for (int n = 0; n < 4; ++n)
      *(f32x4*)&red[w][n*16 + fr][m*16 + fq*4] = acc[m][n];
  __syncthreads();

  const int d = tid >> 2, sub = tid & 3;
  float p[16];
  float mx = -1e30f;
#pragma unroll
  for (int i = 0; i < 16; ++i) {
    const int e = sub * 16 + i;
    float v = red[0][e][d] + red[1][e][d] + red[2][e][d] + red[3][e][d];
    v *= 0.125f;
    p[i] = v; mx = fmaxf(mx, v);
  }
  mx = fmaxf(mx, __shfl_xor(mx, 1, 64));
  mx = fmaxf(mx, __shfl_xor(mx, 2, 64));
  float sm = 0.0f;
#pragma unroll
  for (int i = 0; i < 16; ++i) { p[i] = expf(p[i] - mx); sm += p[i]; }
  sm += __shfl_xor(sm, 1, 64);
  sm += __shfl_xor(sm, 2, 64);
  const float inv = 1.0f / sm;
  us8 o0, o1;
#pragma unroll
  for (int i = 0; i < 8; ++i) { o0[i] = f2bf(p[i] * inv); o1[i] = f2bf(p[i+8] * inv); }
  u16* dst = P + (size_t)bh * 4096 + d * 64 + sub * 16;
  *(us8*)dst = o0;
  *(us8*)(dst + 8) = o1;
}

// ---------------------------------------------------------------------------
// PV via MFMA. out[d][s] = sum_e P[d][e] * V[e][s], V given as v2[s][e].
// Grid (bh=64, sc=8); wave w covers 128 s. Scatter to ar layout:
// ar[b][d*64 + h*4 + (s>>10)][s&1023]
// ---------------------------------------------------------------------------
__global__ void __launch_bounds__(256)
pv2_k(const u16* __restrict__ P, const u16* __restrict__ v2,
      u16* __restrict__ ar)
{
  const int bh = blockIdx.x, sc = blockIdx.y;
  const int b = bh >> 4, h = bh & 15;
  const int tid = threadIdx.x, w = tid >> 6, l = tid & 63;
  const int fr = l & 15, fq = l >> 4;
  const u16* Pb = P + (size_t)bh * 4096;
  const u16* Vb = v2 + (size_t)bh * D_HEAD * S_LEN;

  bf16x8 a[4][2];
#pragma unroll
  for (int m = 0; m < 4; ++m)
#pragma unroll
    for (int ks = 0; ks < 2; ++ks)
      a[m][ks] = *(const bf16x8*)(Pb + (m*16 + fr) * 64 + ks*32 + fq*8);

  const int sw = sc * 512 + w * 128;
  f32x4 acc[8][4] = {};   // [n][m]
#pragma unroll
  for (int n = 0; n < 8; ++n) {
    const u16* vp = Vb + (size_t)(sw + n*16 + fr) * 64 + fq*8;
    const bf16x8 b0 = *(const bf16x8*)(vp);
    const bf16x8 b1 = *(const bf16x8*)(vp + 32);
#pragma unroll
    for (int m = 0; m < 4; ++m)
      acc[n][m] = __builtin_amdgcn_mfma_f32_16x16x32_bf16(a[m][0], b0, acc[n][m], 0, 0, 0);
#pragma unroll
    for (int m = 0; m < 4; ++m)
      acc[n][m] = __builtin_amdgcn_mfma_f32_16x16x32_bf16(a[m][1], b1, acc[n][m], 0, 0, 0);
  }

  const int shi = sc >> 1;
  const int col0 = (sc & 1) * 512 + w * 128;
#pragma unroll
  for (int m = 0; m < 4; ++m)
#pragma unroll
    for (int j = 0; j < 4; ++j) {
      const int d = m*16 + fq*4 + j;
      const size_t base = ((size_t)b * 4096 + (d << 6) + (h << 2) + shi) * 1024 + col0;
#pragma unroll
      for (int n = 0; n < 8; ++n)
        ar[base + n*16 + fr] = f2bf(acc[n][m][j]);
    }
}

// ---------------------------------------------------------------------------
extern "C" void kernel_launch(void* const* d_in, const int* in_sizes, int n_in,
                              void* d_out, int out_size, void* d_ws, size_t ws_size,
                              hipStream_t stream)
{
  const float* x     = (const float*)d_in[0];
  const float* scale = (const float*)d_in[1];
  const float* qw = (const float*)d_in[2];
  const float* qb = (const float*)d_in[3];
  const float* kw = (const float*)d_in[4];
  const float* kb = (const float*)d_in[5];
  const float* vw = (const float*)d_in[6];
  const float* vb = (const float*)d_in[7];
  const float* ow = (const float*)d_in[8];
  const float* ob = (const float*)d_in[9];
  const float* f1w = (const float*)d_in[10];
  const float* f1b = (const float*)d_in[11];
  const float* f2w = (const float*)d_in[12];
  const float* f2b = (const float*)d_in[13];
  float* out = (float*)d_out;

  const size_t TOKD = (size_t)TOKENS * D_MODEL;
  const size_t WSZ1 = (size_t)D_MODEL * D_MODEL;
  const size_t WSZ2 = (size_t)FF_DIM * D_MODEL;
  u16* xn = (u16*)d_ws;
  u16* qt = xn + TOKD;
  u16* kt = qt + TOKD;
  u16* v2 = kt + TOKD;
  u16* wq = v2 + TOKD;
  u16* wk = wq + WSZ1;
  u16* wv = wk + WSZ1;
  u16* wo = wv + WSZ1;
  u16* w1 = wo + WSZ1;
  u16* w2 = w1 + WSZ2;
  u16* Patt = w2 + WSZ2;      // 64*64*64 bf16 = 512KB
  u16* hbuf = kt;             // overlays kt+v2 (dead after attention)
  u16* ar = qt;               // overlays qt (dead after att_sm)

  dim3 blk(256);

  // 0. weights f32 -> bf16 (fused)
  cvt6_k<<<8192, blk, 0, stream>>>(qw, kw, vw, ow, f1w, f2w, wq, wk, wv, wo, w1, w2);
  // 1. rmsnorm(x) -> xn
  rmsnorm_k<<<TOKENS, blk, 0, stream>>>(x, scale, xn);
  // 2. QKV projections: qt/kt [bh][d][s], v2 [bh][s][e]
  mgemm_qkv<<<dim3(TOKENS / 128, D_MODEL / 128, 3), blk, 0, stream>>>(
      xn, wq, wk, wv, qb, kb, vb, qt, kt, v2);
  // 3. scores + softmax -> Patt (bf16 [bh][64][64])
  att_sm_k<<<64, blk, 0, stream>>>(qt, kt, Patt);
  // 4. PV -> ar
  pv2_k<<<dim3(64, 8), blk, 0, stream>>>(Patt, v2, ar);
  // 5. O projection + bias + residual(x) -> out (f32)
  mgemm<2><<<dim3(TOKENS / 128, D_MODEL / 128), blk, 0, stream>>>(
      ar, wo, ob, x, out, D_MODEL, D_MODEL);
  // 6. rmsnorm(out) -> xn
  rmsnorm_k<<<TOKENS, blk, 0, stream>>>(out, scale, xn);
  // 7. FFN up + swiglu -> hbuf
  mgemm<3><<<dim3(TOKENS / 128, FF_DIM / 128), blk, 0, stream>>>(
      xn, w1, f1b, nullptr, hbuf, FF_DIM, D_MODEL);
  // 8. FFN down + bias + residual(out) -> out
  mgemm<2><<<dim3(TOKENS / 128, D_MODEL / 128), blk, 0, stream>>>(
      hbuf, w2, f2b, out, out, D_MODEL, FF_DIM);
}

// Round 5
// 434.250 us; speedup vs baseline: 8.9940x; 1.3175x over previous
//
#include <hip/hip_runtime.h>
#include <math.h>

typedef unsigned short u16;
typedef __attribute__((ext_vector_type(4))) unsigned short us4;
typedef __attribute__((ext_vector_type(8))) unsigned short us8;
typedef __attribute__((ext_vector_type(4))) float f4;
typedef __attribute__((ext_vector_type(8))) short bf16x8;
typedef __attribute__((ext_vector_type(4))) float f32x4;

#define S_LEN   4096
#define D_MODEL 1024
#define N_HEAD  16
#define D_HEAD  64
#define FF_DIM  2048
#define TOKENS  16384  // B*S

__device__ __forceinline__ float bf2f(u16 u) {
  union { float f; unsigned u; } x; x.u = ((unsigned)u) << 16; return x.f;
}
__device__ __forceinline__ u16 f2bf(float f) {
  union { float f; unsigned u; } x; x.f = f;
  return (u16)((x.u + 0x7FFFu + ((x.u >> 16) & 1u)) >> 16);
}

__device__ __forceinline__ void gll16(const void* g, void* l) {
  __builtin_amdgcn_global_load_lds(
      (const __attribute__((address_space(1))) void*)g,
      (__attribute__((address_space(3))) void*)l, 16, 0, 0);
}

// ---------------------------------------------------------------------------
// Fused f32 -> bf16 weight conversion for all 6 weight matrices.
// ---------------------------------------------------------------------------
__global__ void __launch_bounds__(256)
cvt6_k(const float* __restrict__ qw, const float* __restrict__ kw,
       const float* __restrict__ vw, const float* __restrict__ ow,
       const float* __restrict__ f1w, const float* __restrict__ f2w,
       u16* __restrict__ wq, u16* __restrict__ wk, u16* __restrict__ wv,
       u16* __restrict__ wo, u16* __restrict__ w1, u16* __restrict__ w2)
{
  const int id = blockIdx.x;
  const float* src; u16* dst; int base;
  if      (id < 1024) { src = qw;  dst = wq; base = 0; }
  else if (id < 2048) { src = kw;  dst = wk; base = 1024; }
  else if (id < 3072) { src = vw;  dst = wv; base = 2048; }
  else if (id < 4096) { src = ow;  dst = wo; base = 3072; }
  else if (id < 6144) { src = f1w; dst = w1; base = 4096; }
  else                { src = f2w; dst = w2; base = 6144; }
  const size_t i = ((size_t)(id - base) * 256 + threadIdx.x) * 4;
  const f4 v = *(const f4*)(src + i);
  us4 o;
  o[0] = f2bf(v[0]); o[1] = f2bf(v[1]); o[2] = f2bf(v[2]); o[3] = f2bf(v[3]);
  *(us4*)(dst + i) = o;
}

// ---------------------------------------------------------------------------
// RMSNorm: one block per row of 1024. f32 in -> bf16 out.
// ---------------------------------------------------------------------------
__global__ void __launch_bounds__(256)
rmsnorm_k(const float* __restrict__ in, const float* __restrict__ scale,
          u16* __restrict__ out)
{
  const int row = blockIdx.x;
  const int tid = threadIdx.x;
  const f4 v = *(const f4*)(in + (size_t)row * D_MODEL + tid * 4);
  float ss = v[0]*v[0] + v[1]*v[1] + v[2]*v[2] + v[3]*v[3];
#pragma unroll
  for (int off = 32; off > 0; off >>= 1) ss += __shfl_down(ss, off, 64);
  __shared__ float red[4];
  const int wid = tid >> 6, lane = tid & 63;
  if (lane == 0) red[wid] = ss;
  __syncthreads();
  const float tot = red[0] + red[1] + red[2] + red[3];
  const float r = rsqrtf(tot * (1.0f / 1024.0f) + 1e-6f);
  const f4 sc = *(const f4*)(scale + tid * 4);
  us4 o;
  o[0] = f2bf(v[0] * r * sc[0]);
  o[1] = f2bf(v[1] * r * sc[1]);
  o[2] = f2bf(v[2] * r * sc[2]);
  o[3] = f2bf(v[3] * r * sc[3]);
  *(us4*)(out + (size_t)row * D_MODEL + tid * 4) = o;
}

// ---------------------------------------------------------------------------
// 256x256 8-phase GEMM (T2 swizzle + T3/T4 counted vmcnt + T5 setprio).
// 512 threads = 8 waves (2M x 4N). BK=64, double-buffered LDS (128 KiB).
// Gray-code phase order per tile: (mh,nh) = (0,0),(0,1),(1,1),(1,0).
// Rolling stage (one half-tile per phase), each STAGE lands >=1 barrier
// after the last ds_read of its destination region:
//   q0: B h0 of t+1 | q1: B h1 of t+1 | q2: A h0 of t+2 | q3: A h1 of t+2
// stage->first-read distance >= 4 phases; end-of-phase vmcnt(6) (= 3
// half-tiles / 6 loads in flight) provably drains each target pre-read.
// EPI 0: QKV (W = concat [3072][1024]); z = blockIdx.y>>2:
//        z<2 -> transpose scatter to [bh][d][s]; z=2 -> v2 [bh][s][d].
// EPI 2: f32 out = acc + bias + res.   EPI 3: bf16 swiglu out.
// ---------------------------------------------------------------------------
template<int EPI>
__global__ __launch_bounds__(512, 2)
void g8k(const u16* __restrict__ Ag, const u16* __restrict__ Wg,
         const float* __restrict__ bq, const float* __restrict__ bk,
         const float* __restrict__ bv, const float* __restrict__ res,
         void* __restrict__ C0, void* __restrict__ C1, void* __restrict__ C2,
         int N, int K)
{
  __shared__ __align__(16) u16 lds[65536];   // A: [0,32768) B: [32768,65536)
  const int tid = threadIdx.x;
  const int w = tid >> 6, l = tid & 63;
  const int fr = l & 15, fq = l >> 4;
  const int wm = w >> 2, wn = w & 3;
  const int m0 = blockIdx.x << 8, n0 = blockIdx.y << 8;
  const int srow = w * 8 + (l >> 3);
  const int scol = ((l & 7) ^ (l >> 3)) << 3;  // inverse-swizzled source col (u16)
  const int NT = K >> 6;

  auto STAGE = [&](int isA, int hf, int bfs, int nt) {
    const u16* G = isA ? Ag : Wg;
    const int rb = (isA ? m0 : n0) + hf * 128 + srow;
    const int ks = (nt < NT ? nt << 6 : 0) + scol;
    u16* lb = lds + (isA ? 0 : 32768) + bfs * 16384 + hf * 8192 + w * 512;
    gll16(G + (size_t)rb * K + ks, lb);
    gll16(G + (size_t)(rb + 64) * K + ks, lb + 4096);
  };

  f32x4 acc[8][4] = {};
  bf16x8 afr[4][2], bfr[2][2];

  // prologue: tile0 all 4 halves + A h0/h1 of tile1 = 6 STAGEs (12 loads)
  STAGE(1, 0, 0, 0);  // A h0 t0   (loads 1,2)
  STAGE(0, 0, 0, 0);  // B h0 t0   (loads 3,4)
  STAGE(0, 1, 0, 0);  // B h1 t0   (loads 5,6)
  STAGE(1, 1, 0, 0);  // A h1 t0   (loads 7,8)
  STAGE(1, 0, 1, 1);  // A h0 t1   (loads 9,10)
  STAGE(1, 1, 1, 1);  // A h1 t1   (loads 11,12)
  asm volatile("s_waitcnt vmcnt(8)" ::: "memory");   // drain A h0 t0 + B h0 t0
  __builtin_amdgcn_s_barrier();

  const int NIT = K >> 7;
  for (int it = 0; it < NIT; ++it) {
#pragma unroll
    for (int p = 0; p < 8; ++p) {
      const int q = p & 3;
      const int bf = (p >> 2) & 1;            // current tile parity
      const int n = 2 * it + (p >> 2);        // current tile index
      const int mh = (q >> 1) & 1;            // 0,0,1,1
      const int nh = (q == 1 || q == 2) ? 1 : 0;  // 0,1,1,0 (gray)
      if ((q & 1) == 0) {   // q==0 / q==2: (re)load A-half mh
#pragma unroll
        for (int i = 0; i < 4; ++i)
#pragma unroll
          for (int kk = 0; kk < 2; ++kk) {
            const int rh = i * 32 + wm * 16 + fr;
            afr[i][kk] = *(const bf16x8*)(lds + bf * 16384 + mh * 8192 + rh * 64
                                          + ((kk * 32 + fq * 8) ^ ((fr & 7) << 3)));
          }
      }
      if (q != 2) {         // q==2 reuses bfr (B h1) from q==1
#pragma unroll
        for (int jn = 0; jn < 2; ++jn)
#pragma unroll
          for (int kk = 0; kk < 2; ++kk) {
            const int rh = jn * 64 + wn * 16 + fr;
            bfr[jn][kk] = *(const bf16x8*)(lds + 32768 + bf * 16384 + nh * 8192 + rh * 64
                                           + ((kk * 32 + fq * 8) ^ ((fr & 7) << 3)));
          }
      }
      // rolling stage: one half-tile per phase (write-safe by schedule)
      if      (q == 0) STAGE(0, 0, bf ^ 1, n + 1);  // B h0 of t+1
      else if (q == 1) STAGE(0, 1, bf ^ 1, n + 1);  // B h1 of t+1
      else if (q == 2) STAGE(1, 0, bf,     n + 2);  // A h0 of t+2
      else             STAGE(1, 1, bf,     n + 2);  // A h1 of t+2
      __builtin_amdgcn_s_barrier();
      asm volatile("s_waitcnt lgkmcnt(0)" ::: "memory");
      __builtin_amdgcn_sched_barrier(0);
      __builtin_amdgcn_s_setprio(1);
#pragma unroll
      for (int i = 0; i < 4; ++i)
#pragma unroll
        for (int jn = 0; jn < 2; ++jn)
#pragma unroll
          for (int kk = 0; kk < 2; ++kk)
            acc[mh * 4 + i][nh * 2 + jn] =
                __builtin_amdgcn_mfma_f32_16x16x32_bf16(afr[i][kk], bfr[jn][kk],
                                                        acc[mh * 4 + i][nh * 2 + jn], 0, 0, 0);
      __builtin_amdgcn_s_setprio(0);
      asm volatile("s_waitcnt vmcnt(6)" ::: "memory");
      __builtin_amdgcn_s_barrier();
    }
  }
  asm volatile("s_waitcnt vmcnt(0)" ::: "memory");
  __builtin_amdgcn_s_barrier();

  if constexpr (EPI == 2) {
    float* C = (float*)C0;
#pragma unroll
    for (int mi = 0; mi < 8; ++mi)
#pragma unroll
      for (int ni = 0; ni < 4; ++ni) {
        const int c = n0 + ni * 64 + wn * 16 + fr;
        const int r0 = m0 + mi * 32 + wm * 16 + fq * 4;
        const float bb = bq[c];
#pragma unroll
        for (int j = 0; j < 4; ++j)
          C[(size_t)(r0 + j) * N + c] = acc[mi][ni][j] + bb + res[(size_t)(r0 + j) * N + c];
      }
  } else if constexpr (EPI == 3) {
    u16* C = (u16*)C0;
#pragma unroll
    for (int mi = 0; mi < 8; ++mi)
#pragma unroll
      for (int ni = 0; ni < 4; ++ni) {
        const int c = n0 + ni * 64 + wn * 16 + fr;
        const int r0 = m0 + mi * 32 + wm * 16 + fq * 4;
        const float bb = bq[c];
#pragma unroll
        for (int j = 0; j < 4; ++j) {
          const float v = acc[mi][ni][j] + bb;
          const float sig = 1.0f / (1.0f + expf(-v));
          C[(size_t)(r0 + j) * N + c] = f2bf(v * sig + v);
        }
      }
  } else {
    // QKV epilogue: pack bias-added bf16 tile transposed into LDS (swizzled)
    const int z = blockIdx.y >> 2;
    const float* bias = z == 0 ? bq : (z == 1 ? bk : bv);
    const int n0l = n0 & 1023;
    const int bb = m0 >> 12, s0l = m0 & (S_LEN - 1);
#pragma unroll
    for (int mi = 0; mi < 8; ++mi)
#pragma unroll
      for (int ni = 0; ni < 4; ++ni) {
        const int c = ni * 64 + wn * 16 + fr;
        const int r0 = mi * 32 + wm * 16 + fq * 4;
        const float bv_ = bias[n0l + c];
        us4 pk;
#pragma unroll
        for (int j = 0; j < 4; ++j) pk[j] = f2bf(acc[mi][ni][j] + bv_);
        const int byte = ((c << 9) + (r0 << 1)) ^ ((c & 7) << 4);
        *(us4*)((char*)lds + byte) = pk;
      }
    __syncthreads();
    if (z < 2) {
      u16* Cout = z == 0 ? (u16*)C0 : (u16*)C1;
      const int c = tid & 255, half = tid >> 8;
      const int o = n0l + c, d = o >> 4, h = o & 15;
      const int xr = (c & 7) << 4;
      u16* dst = Cout + ((size_t)((bb << 10) + (h << 6) + d)) * S_LEN + s0l + half * 128;
#pragma unroll
      for (int u = 0; u < 16; ++u) {
        const int byte = ((c << 9) + (half << 8) + (u << 4)) ^ xr;
        const us8 v = *(const us8*)((char*)lds + byte);
        *(us8*)(dst + u * 8) = v;
      }
    } else {
      u16* Cv = (u16*)C2;
      const int d0 = n0l >> 4;
#pragma unroll
      for (int q2 = 0; q2 < 8; ++q2) {
        const int idx = q2 * 512 + tid;
        const int h = idx >> 8, r = idx & 255;
        const int xr = (h & 7) << 4;
        us8 lo, hi;
#pragma unroll
        for (int dl = 0; dl < 8; ++dl) {
          lo[dl] = *(const u16*)((char*)lds + ((((h + dl * 16) << 9) + (r << 1)) ^ xr));
          hi[dl] = *(const u16*)((char*)lds + ((((h + (dl + 8) * 16) << 9) + (r << 1)) ^ xr));
        }
        u16* dst = Cv + ((size_t)(bb * 16 + h) * S_LEN + s0l + r) * 64 + d0;
        *(us8*)dst = lo;
        *(us8*)(dst + 8) = hi;
      }
    }
  }
}

// ---------------------------------------------------------------------------
// Fused scores + softmax per (b,h). One block per bh, 4 waves.
// ---------------------------------------------------------------------------
__global__ void __launch_bounds__(256)
att_sm_k(const u16* __restrict__ qt, const u16* __restrict__ kt,
         u16* __restrict__ P)
{
  __shared__ float red[4][64][64];   // [wave][e][d]
  const int bh = blockIdx.x;
  const int tid = threadIdx.x, w = tid >> 6, l = tid & 63;
  const int fr = l & 15, fq = l >> 4;
  const u16* Qb = qt + (size_t)bh * D_HEAD * S_LEN;
  const u16* Kb = kt + (size_t)bh * D_HEAD * S_LEN;
  f32x4 acc[4][4] = {};
  const int sb = w * 1024 + fq * 8;
  for (int ks = 0; ks < 32; ++ks) {
    const int s0 = sb + ks * 32;
    bf16x8 a[4], b[4];
#pragma unroll
    for (int m = 0; m < 4; ++m)
      a[m] = *(const bf16x8*)(Qb + (size_t)(m*16 + fr) * S_LEN + s0);
#pragma unroll
    for (int n = 0; n < 4; ++n)
      b[n] = *(const bf16x8*)(Kb + (size_t)(n*16 + fr) * S_LEN + s0);
#pragma unroll
    for (int m = 0; m < 4; ++m)
#pragma unroll
      for (int n = 0; n < 4; ++n)
        acc[m][n] = __builtin_amdgcn_mfma_f32_16x16x32_bf16(a[m], b[n], acc[m][n], 0, 0, 0);
  }
#pragma unroll
  for (int m = 0; m < 4; ++m)
#pragma unroll
    for (int n = 0; n < 4; ++n)
      *(f32x4*)&red[w][n*16 + fr][m*16 + fq*4] = acc[m][n];
  __syncthreads();

  const int d = tid >> 2, sub = tid & 3;
  float p[16];
  float mx = -1e30f;
#pragma unroll
  for (int i = 0; i < 16; ++i) {
    const int e = sub * 16 + i;
    float v = red[0][e][d] + red[1][e][d] + red[2][e][d] + red[3][e][d];
    v *= 0.125f;
    p[i] = v; mx = fmaxf(mx, v);
  }
  mx = fmaxf(mx, __shfl_xor(mx, 1, 64));
  mx = fmaxf(mx, __shfl_xor(mx, 2, 64));
  float sm = 0.0f;
#pragma unroll
  for (int i = 0; i < 16; ++i) { p[i] = expf(p[i] - mx); sm += p[i]; }
  sm += __shfl_xor(sm, 1, 64);
  sm += __shfl_xor(sm, 2, 64);
  const float inv = 1.0f / sm;
  us8 o0, o1;
#pragma unroll
  for (int i = 0; i < 8; ++i) { o0[i] = f2bf(p[i] * inv); o1[i] = f2bf(p[i+8] * inv); }
  u16* dst = P + (size_t)bh * 4096 + d * 64 + sub * 16;
  *(us8*)dst = o0;
  *(us8*)(dst + 8) = o1;
}

// ---------------------------------------------------------------------------
// PV via MFMA. out[d][s] = sum_e P[d][e] * V[e][s], V given as v2[s][e].
// ---------------------------------------------------------------------------
__global__ void __launch_bounds__(256)
pv2_k(const u16* __restrict__ P, const u16* __restrict__ v2,
      u16* __restrict__ ar)
{
  const int bh = blockIdx.x, sc = blockIdx.y;
  const int b = bh >> 4, h = bh & 15;
  const int tid = threadIdx.x, w = tid >> 6, l = tid & 63;
  const int fr = l & 15, fq = l >> 4;
  const u16* Pb = P + (size_t)bh * 4096;
  const u16* Vb = v2 + (size_t)bh * D_HEAD * S_LEN;

  bf16x8 a[4][2];
#pragma unroll
  for (int m = 0; m < 4; ++m)
#pragma unroll
    for (int ks = 0; ks < 2; ++ks)
      a[m][ks] = *(const bf16x8*)(Pb + (m*16 + fr) * 64 + ks*32 + fq*8);

  const int sw = sc * 512 + w * 128;
  f32x4 acc[8][4] = {};   // [n][m]
#pragma unroll
  for (int n = 0; n < 8; ++n) {
    const u16* vp = Vb + (size_t)(sw + n*16 + fr) * 64 + fq*8;
    const bf16x8 b0 = *(const bf16x8*)(vp);
    const bf16x8 b1 = *(const bf16x8*)(vp + 32);
#pragma unroll
    for (int m = 0; m < 4; ++m)
      acc[n][m] = __builtin_amdgcn_mfma_f32_16x16x32_bf16(a[m][0], b0, acc[n][m], 0, 0, 0);
#pragma unroll
    for (int m = 0; m < 4; ++m)
      acc[n][m] = __builtin_amdgcn_mfma_f32_16x16x32_bf16(a[m][1], b1, acc[n][m], 0, 0, 0);
  }

  const int shi = sc >> 1;
  const int col0 = (sc & 1) * 512 + w * 128;
#pragma unroll
  for (int m = 0; m < 4; ++m)
#pragma unroll
    for (int j = 0; j < 4; ++j) {
      const int d = m*16 + fq*4 + j;
      const size_t base = ((size_t)b * 4096 + (d << 6) + (h << 2) + shi) * 1024 + col0;
#pragma unroll
      for (int n = 0; n < 8; ++n)
        ar[base + n*16 + fr] = f2bf(acc[n][m][j]);
    }
}

// ---------------------------------------------------------------------------
extern "C" void kernel_launch(void* const* d_in, const int* in_sizes, int n_in,
                              void* d_out, int out_size, void* d_ws, size_t ws_size,
                              hipStream_t stream)
{
  const float* x     = (const float*)d_in[0];
  const float* scale = (const float*)d_in[1];
  const float* qw = (const float*)d_in[2];
  const float* qb = (const float*)d_in[3];
  const float* kw = (const float*)d_in[4];
  const float* kb = (const float*)d_in[5];
  const float* vw = (const float*)d_in[6];
  const float* vb = (const float*)d_in[7];
  const float* ow = (const float*)d_in[8];
  const float* ob = (const float*)d_in[9];
  const float* f1w = (const float*)d_in[10];
  const float* f1b = (const float*)d_in[11];
  const float* f2w = (const float*)d_in[12];
  const float* f2b = (const float*)d_in[13];
  float* out = (float*)d_out;

  const size_t TOKD = (size_t)TOKENS * D_MODEL;
  const size_t WSZ1 = (size_t)D_MODEL * D_MODEL;
  const size_t WSZ2 = (size_t)FF_DIM * D_MODEL;
  u16* xn = (u16*)d_ws;
  u16* qt = xn + TOKD;
  u16* kt = qt + TOKD;
  u16* v2 = kt + TOKD;
  u16* wq = v2 + TOKD;        // wq,wk,wv contiguous = concat [3072][1024]
  u16* wk = wq + WSZ1;
  u16* wv = wk + WSZ1;
  u16* wo = wv + WSZ1;
  u16* w1 = wo + WSZ1;
  u16* w2 = w1 + WSZ2;
  u16* Patt = w2 + WSZ2;
  u16* hbuf = kt;             // overlays kt+v2 (dead after attention)
  u16* ar = qt;               // overlays qt (dead after att_sm)

  dim3 blk(256);
  dim3 blk8(512);

  // 0. weights f32 -> bf16
  cvt6_k<<<8192, blk, 0, stream>>>(qw, kw, vw, ow, f1w, f2w, wq, wk, wv, wo, w1, w2);
  // 1. rmsnorm(x) -> xn
  rmsnorm_k<<<TOKENS, blk, 0, stream>>>(x, scale, xn);
  // 2. QKV (merged N=3072): qt/kt [bh][d][s], v2 [bh][s][d]
  g8k<0><<<dim3(TOKENS / 256, 12), blk8, 0, stream>>>(
      xn, wq, qb, kb, vb, nullptr, qt, kt, v2, 3072, D_MODEL);
  // 3. scores + softmax -> Patt
  att_sm_k<<<64, blk, 0, stream>>>(qt, kt, Patt);
  // 4. PV -> ar
  pv2_k<<<dim3(64, 8), blk, 0, stream>>>(Patt, v2, ar);
  // 5. O projection + bias + residual(x) -> out (f32)
  g8k<2><<<dim3(TOKENS / 256, D_MODEL / 256), blk8, 0, stream>>>(
      ar, wo, ob, nullptr, nullptr, x, out, nullptr, nullptr, D_MODEL, D_MODEL);
  // 6. rmsnorm(out) -> xn
  rmsnorm_k<<<TOKENS, blk, 0, stream>>>(out, scale, xn);
  // 7. FFN up + swiglu -> hbuf
  g8k<3><<<dim3(TOKENS / 256, FF_DIM / 256), blk8, 0, stream>>>(
      xn, w1, f1b, nullptr, nullptr, nullptr, hbuf, nullptr, nullptr, FF_DIM, D_MODEL);
  // 8. FFN down + bias + residual(out) -> out
  g8k<2><<<dim3(TOKENS / 256, D_MODEL / 256), blk8, 0, stream>>>(
      hbuf, w2, f2b, nullptr, nullptr, out, out, nullptr, nullptr, D_MODEL, FF_DIM);
}

// Round 6
// 432.934 us; speedup vs baseline: 9.0214x; 1.0030x over previous
//
#include <hip/hip_runtime.h>
#include <math.h>

typedef unsigned short u16;
typedef __attribute__((ext_vector_type(4))) unsigned short us4;
typedef __attribute__((ext_vector_type(8))) unsigned short us8;
typedef __attribute__((ext_vector_type(4))) float f4;
typedef __attribute__((ext_vector_type(8))) short bf16x8;
typedef __attribute__((ext_vector_type(4))) float f32x4;

#define S_LEN   4096
#define D_MODEL 1024
#define N_HEAD  16
#define D_HEAD  64
#define FF_DIM  2048
#define TOKENS  16384  // B*S

__device__ __forceinline__ float bf2f(u16 u) {
  union { float f; unsigned u; } x; x.u = ((unsigned)u) << 16; return x.f;
}
__device__ __forceinline__ u16 f2bf(float f) {
  union { float f; unsigned u; } x; x.f = f;
  return (u16)((x.u + 0x7FFFu + ((x.u >> 16) & 1u)) >> 16);
}

__device__ __forceinline__ void gll16(const void* g, void* l) {
  __builtin_amdgcn_global_load_lds(
      (const __attribute__((address_space(1))) void*)g,
      (__attribute__((address_space(3))) void*)l, 16, 0, 0);
}

// barrier + compiler-only memory fence (no extra waits at runtime)
#define BARF() do { __builtin_amdgcn_s_barrier(); asm volatile("" ::: "memory"); } while (0)

// ---------------------------------------------------------------------------
// Fused f32 -> bf16 weight conversion for all 6 weight matrices.
// ---------------------------------------------------------------------------
__global__ void __launch_bounds__(256)
cvt6_k(const float* __restrict__ qw, const float* __restrict__ kw,
       const float* __restrict__ vw, const float* __restrict__ ow,
       const float* __restrict__ f1w, const float* __restrict__ f2w,
       u16* __restrict__ wq, u16* __restrict__ wk, u16* __restrict__ wv,
       u16* __restrict__ wo, u16* __restrict__ w1, u16* __restrict__ w2)
{
  const int id = blockIdx.x;
  const float* src; u16* dst; int base;
  if      (id < 1024) { src = qw;  dst = wq; base = 0; }
  else if (id < 2048) { src = kw;  dst = wk; base = 1024; }
  else if (id < 3072) { src = vw;  dst = wv; base = 2048; }
  else if (id < 4096) { src = ow;  dst = wo; base = 3072; }
  else if (id < 6144) { src = f1w; dst = w1; base = 4096; }
  else                { src = f2w; dst = w2; base = 6144; }
  const size_t i = ((size_t)(id - base) * 256 + threadIdx.x) * 4;
  const f4 v = *(const f4*)(src + i);
  us4 o;
  o[0] = f2bf(v[0]); o[1] = f2bf(v[1]); o[2] = f2bf(v[2]); o[3] = f2bf(v[3]);
  *(us4*)(dst + i) = o;
}

// ---------------------------------------------------------------------------
// RMSNorm: one block per row of 1024. f32 in -> bf16 out.
// ---------------------------------------------------------------------------
__global__ void __launch_bounds__(256)
rmsnorm_k(const float* __restrict__ in, const float* __restrict__ scale,
          u16* __restrict__ out)
{
  const int row = blockIdx.x;
  const int tid = threadIdx.x;
  const f4 v = *(const f4*)(in + (size_t)row * D_MODEL + tid * 4);
  float ss = v[0]*v[0] + v[1]*v[1] + v[2]*v[2] + v[3]*v[3];
#pragma unroll
  for (int off = 32; off > 0; off >>= 1) ss += __shfl_down(ss, off, 64);
  __shared__ float red[4];
  const int wid = tid >> 6, lane = tid & 63;
  if (lane == 0) red[wid] = ss;
  __syncthreads();
  const float tot = red[0] + red[1] + red[2] + red[3];
  const float r = rsqrtf(tot * (1.0f / 1024.0f) + 1e-6f);
  const f4 sc = *(const f4*)(scale + tid * 4);
  us4 o;
  o[0] = f2bf(v[0] * r * sc[0]);
  o[1] = f2bf(v[1] * r * sc[1]);
  o[2] = f2bf(v[2] * r * sc[2]);
  o[3] = f2bf(v[3] * r * sc[3]);
  *(us4*)(out + (size_t)row * D_MODEL + tid * 4) = o;
}

// ---------------------------------------------------------------------------
// 256x256 8-phase GEMM (T2 swizzle + T3/T4 counted vmcnt + T5 setprio).
// 512 threads = 8 waves (2M x 4N). BK=64, double-buffered LDS (128 KiB).
// Gray-code phase order per tile: (mh,nh) = (0,0),(0,1),(1,1),(1,0).
// Rolling stage, one half-tile per phase:
//   q0: B h0 of t+1 | q1: B h1 of t+1 | q2: A h0 of t+2 | q3: A h1 of t+2
// Per-phase STAGE target is disjoint from that phase's ds_reads; each STAGE
// lands >=1 barrier after the last ds_read-issue of its region.
// Single vmcnt(4) per K-tile (at q3): keeps only {A h0,h1 of t+2} in flight,
// drains exactly what tile t+1 reads. Prologue drains to the same state.
// No manual lgkmcnt / sched_barrier: compiler emits fine-grained lgkm waits.
// EPI 0: QKV (W = concat [3072][1024]); z = blockIdx.y>>2:
//        z<2 -> transpose scatter to [bh][d][s]; z=2 -> v2 [bh][s][d].
// EPI 2: f32 out = acc + bias + res.   EPI 3: bf16 swiglu out.
// ---------------------------------------------------------------------------
template<int EPI>
__global__ __launch_bounds__(512, 2)
void g8k(const u16* __restrict__ Ag, const u16* __restrict__ Wg,
         const float* __restrict__ bq, const float* __restrict__ bk,
         const float* __restrict__ bv, const float* __restrict__ res,
         void* __restrict__ C0, void* __restrict__ C1, void* __restrict__ C2,
         int N, int K)
{
  __shared__ __align__(16) u16 lds[65536];   // A: [0,32768) B: [32768,65536)
  const int tid = threadIdx.x;
  const int w = tid >> 6, l = tid & 63;
  const int fr = l & 15, fq = l >> 4;
  const int wm = w >> 2, wn = w & 3;
  const int m0 = blockIdx.x << 8, n0 = blockIdx.y << 8;
  const int srow = w * 8 + (l >> 3);
  const int scol = ((l & 7) ^ (l >> 3)) << 3;  // inverse-swizzled source col (u16)
  const int NT = K >> 6;

  auto STAGE = [&](int isA, int hf, int bfs, int nt) {
    const u16* G = isA ? Ag : Wg;
    const int rb = (isA ? m0 : n0) + hf * 128 + srow;
    const int ks = (nt < NT ? nt << 6 : 0) + scol;
    u16* lb = lds + (isA ? 0 : 32768) + bfs * 16384 + hf * 8192 + w * 512;
    gll16(G + (size_t)rb * K + ks, lb);
    gll16(G + (size_t)(rb + 64) * K + ks, lb + 4096);
  };

  f32x4 acc[8][4] = {};
  bf16x8 afr[4][2], bfr[2][2];

  auto LDA = [&](int bf, int mh) {
#pragma unroll
    for (int i = 0; i < 4; ++i)
#pragma unroll
      for (int kk = 0; kk < 2; ++kk)
        afr[i][kk] = *(const bf16x8*)(lds + bf * 16384 + mh * 8192
                                      + (i * 32 + wm * 16 + fr) * 64
                                      + ((kk * 32 + fq * 8) ^ ((fr & 7) << 3)));
  };
  auto LDB = [&](int bf, int nh) {
#pragma unroll
    for (int jn = 0; jn < 2; ++jn)
#pragma unroll
      for (int kk = 0; kk < 2; ++kk)
        bfr[jn][kk] = *(const bf16x8*)(lds + 32768 + bf * 16384 + nh * 8192
                                       + (jn * 64 + wn * 16 + fr) * 64
                                       + ((kk * 32 + fq * 8) ^ ((fr & 7) << 3)));
  };
  auto MM = [&](int mhalf, int nhalf) {
    __builtin_amdgcn_s_setprio(1);
#pragma unroll
    for (int i = 0; i < 4; ++i)
#pragma unroll
      for (int jn = 0; jn < 2; ++jn)
#pragma unroll
        for (int kk = 0; kk < 2; ++kk)
          acc[mhalf * 4 + i][nhalf * 2 + jn] =
              __builtin_amdgcn_mfma_f32_16x16x32_bf16(afr[i][kk], bfr[jn][kk],
                                                      acc[mhalf * 4 + i][nhalf * 2 + jn], 0, 0, 0);
    __builtin_amdgcn_s_setprio(0);
  };

  // prologue: tile0 all 4 halves + A h0/h1 of tile1 (6 stages, 12 loads)
  STAGE(1, 0, 0, 0);  // A h0 t0
  STAGE(0, 0, 0, 0);  // B h0 t0
  STAGE(0, 1, 0, 0);  // B h1 t0
  STAGE(1, 1, 0, 0);  // A h1 t0
  STAGE(1, 0, 1, 1);  // A h0 t1
  STAGE(1, 1, 1, 1);  // A h1 t1
  asm volatile("s_waitcnt vmcnt(4)" ::: "memory");   // drain all of tile0
  BARF();

  const int NIT = K >> 7;
  for (int it = 0; it < NIT; ++it) {
#pragma unroll
    for (int hf2 = 0; hf2 < 2; ++hf2) {
      const int n = 2 * it + hf2;
      const int bf = n & 1;
      // ---- q0: (mh,nh)=(0,0)
      LDA(bf, 0); LDB(bf, 0);
      STAGE(0, 0, bf ^ 1, n + 1);       // B h0 of t+1
      BARF();
      MM(0, 0);
      BARF();
      // ---- q1: (0,1)
      LDB(bf, 1);
      STAGE(0, 1, bf ^ 1, n + 1);       // B h1 of t+1
      BARF();
      MM(0, 1);
      BARF();
      // ---- q2: (1,1)  (reuses bfr = B h1)
      LDA(bf, 1);
      STAGE(1, 0, bf, n + 2);           // A h0 of t+2
      BARF();
      MM(1, 1);
      BARF();
      // ---- q3: (1,0)
      LDB(bf, 0);
      STAGE(1, 1, bf, n + 2);           // A h1 of t+2
      BARF();
      MM(1, 0);
      asm volatile("s_waitcnt vmcnt(4)" ::: "memory");  // once per K-tile
      BARF();
    }
  }
  asm volatile("s_waitcnt vmcnt(0)" ::: "memory");
  __builtin_amdgcn_s_barrier();
  asm volatile("" ::: "memory");

  if constexpr (EPI == 2) {
    float* C = (float*)C0;
#pragma unroll
    for (int mi = 0; mi < 8; ++mi)
#pragma unroll
      for (int ni = 0; ni < 4; ++ni) {
        const int c = n0 + ni * 64 + wn * 16 + fr;
        const int r0 = m0 + mi * 32 + wm * 16 + fq * 4;
        const float bb = bq[c];
#pragma unroll
        for (int j = 0; j < 4; ++j)
          C[(size_t)(r0 + j) * N + c] = acc[mi][ni][j] + bb + res[(size_t)(r0 + j) * N + c];
      }
  } else if constexpr (EPI == 3) {
    u16* C = (u16*)C0;
#pragma unroll
    for (int mi = 0; mi < 8; ++mi)
#pragma unroll
      for (int ni = 0; ni < 4; ++ni) {
        const int c = n0 + ni * 64 + wn * 16 + fr;
        const int r0 = m0 + mi * 32 + wm * 16 + fq * 4;
        const float bb = bq[c];
#pragma unroll
        for (int j = 0; j < 4; ++j) {
          const float v = acc[mi][ni][j] + bb;
          const float sig = 1.0f / (1.0f + expf(-v));
          C[(size_t)(r0 + j) * N + c] = f2bf(v * sig + v);
        }
      }
  } else {
    // QKV epilogue: pack bias-added bf16 tile transposed into LDS (swizzled)
    const int z = blockIdx.y >> 2;
    const float* bias = z == 0 ? bq : (z == 1 ? bk : bv);
    const int n0l = n0 & 1023;
    const int bb = m0 >> 12, s0l = m0 & (S_LEN - 1);
#pragma unroll
    for (int mi = 0; mi < 8; ++mi)
#pragma unroll
      for (int ni = 0; ni < 4; ++ni) {
        const int c = ni * 64 + wn * 16 + fr;
        const int r0 = mi * 32 + wm * 16 + fq * 4;
        const float bv_ = bias[n0l + c];
        us4 pk;
#pragma unroll
        for (int j = 0; j < 4; ++j) pk[j] = f2bf(acc[mi][ni][j] + bv_);
        const int byte = ((c << 9) + (r0 << 1)) ^ ((c & 7) << 4);
        *(us4*)((char*)lds + byte) = pk;
      }
    __syncthreads();
    if (z < 2) {
      u16* Cout = z == 0 ? (u16*)C0 : (u16*)C1;
      const int c = tid & 255, half = tid >> 8;
      const int o = n0l + c, d = o >> 4, h = o & 15;
      const int xr = (c & 7) << 4;
      u16* dst = Cout + ((size_t)((bb << 10) + (h << 6) + d)) * S_LEN + s0l + half * 128;
#pragma unroll
      for (int u = 0; u < 16; ++u) {
        const int byte = ((c << 9) + (half << 8) + (u << 4)) ^ xr;
        const us8 v = *(const us8*)((char*)lds + byte);
        *(us8*)(dst + u * 8) = v;
      }
    } else {
      u16* Cv = (u16*)C2;
      const int d0 = n0l >> 4;
#pragma unroll
      for (int q2 = 0; q2 < 8; ++q2) {
        const int idx = q2 * 512 + tid;
        const int h = idx >> 8, r = idx & 255;
        const int xr = (h & 7) << 4;
        us8 lo, hi;
#pragma unroll
        for (int dl = 0; dl < 8; ++dl) {
          lo[dl] = *(const u16*)((char*)lds + ((((h + dl * 16) << 9) + (r << 1)) ^ xr));
          hi[dl] = *(const u16*)((char*)lds + ((((h + (dl + 8) * 16) << 9) + (r << 1)) ^ xr));
        }
        u16* dst = Cv + ((size_t)(bb * 16 + h) * S_LEN + s0l + r) * 64 + d0;
        *(us8*)dst = lo;
        *(us8*)(dst + 8) = hi;
      }
    }
  }
}

// ---------------------------------------------------------------------------
// Fused scores + softmax per (b,h). One block per bh, 4 waves.
// ---------------------------------------------------------------------------
__global__ void __launch_bounds__(256)
att_sm_k(const u16* __restrict__ qt, const u16* __restrict__ kt,
         u16* __restrict__ P)
{
  __shared__ float red[4][64][64];   // [wave][e][d]
  const int bh = blockIdx.x;
  const int tid = threadIdx.x, w = tid >> 6, l = tid & 63;
  const int fr = l & 15, fq = l >> 4;
  const u16* Qb = qt + (size_t)bh * D_HEAD * S_LEN;
  const u16* Kb = kt + (size_t)bh * D_HEAD * S_LEN;
  f32x4 acc[4][4] = {};
  const int sb = w * 1024 + fq * 8;
  for (int ks = 0; ks < 32; ++ks) {
    const int s0 = sb + ks * 32;
    bf16x8 a[4], b[4];
#pragma unroll
    for (int m = 0; m < 4; ++m)
      a[m] = *(const bf16x8*)(Qb + (size_t)(m*16 + fr) * S_LEN + s0);
#pragma unroll
    for (int n = 0; n < 4; ++n)
      b[n] = *(const bf16x8*)(Kb + (size_t)(n*16 + fr) * S_LEN + s0);
#pragma unroll
    for (int m = 0; m < 4; ++m)
#pragma unroll
      for (int n = 0; n < 4; ++n)
        acc[m][n] = __builtin_amdgcn_mfma_f32_16x16x32_bf16(a[m], b[n], acc[m][n], 0, 0, 0);
  }
#pragma unroll
  for (int m = 0; m < 4; ++m)
#pragma unroll
    for (int n = 0; n < 4; ++n)
      *(f32x4*)&red[w][n*16 + fr][m*16 + fq*4] = acc[m][n];
  __syncthreads();

  const int d = tid >> 2, sub = tid & 3;
  float p[16];
  float mx = -1e30f;
#pragma unroll
  for (int i = 0; i < 16; ++i) {
    const int e = sub * 16 + i;
    float v = red[0][e][d] + red[1][e][d] + red[2][e][d] + red[3][e][d];
    v *= 0.125f;
    p[i] = v; mx = fmaxf(mx, v);
  }
  mx = fmaxf(mx, __shfl_xor(mx, 1, 64));
  mx = fmaxf(mx, __shfl_xor(mx, 2, 64));
  float sm = 0.0f;
#pragma unroll
  for (int i = 0; i < 16; ++i) { p[i] = expf(p[i] - mx); sm += p[i]; }
  sm += __shfl_xor(sm, 1, 64);
  sm += __shfl_xor(sm, 2, 64);
  const float inv = 1.0f / sm;
  us8 o0, o1;
#pragma unroll
  for (int i = 0; i < 8; ++i) { o0[i] = f2bf(p[i] * inv); o1[i] = f2bf(p[i+8] * inv); }
  u16* dst = P + (size_t)bh * 4096 + d * 64 + sub * 16;
  *(us8*)dst = o0;
  *(us8*)(dst + 8) = o1;
}

// ---------------------------------------------------------------------------
// PV via MFMA. out[d][s] = sum_e P[d][e] * V[e][s], V given as v2[s][e].
// ---------------------------------------------------------------------------
__global__ void __launch_bounds__(256)
pv2_k(const u16* __restrict__ P, const u16* __restrict__ v2,
      u16* __restrict__ ar)
{
  const int bh = blockIdx.x, sc = blockIdx.y;
  const int b = bh >> 4, h = bh & 15;
  const int tid = threadIdx.x, w = tid >> 6, l = tid & 63;
  const int fr = l & 15, fq = l >> 4;
  const u16* Pb = P + (size_t)bh * 4096;
  const u16* Vb = v2 + (size_t)bh * D_HEAD * S_LEN;

  bf16x8 a[4][2];
#pragma unroll
  for (int m = 0; m < 4; ++m)
#pragma unroll
    for (int ks = 0; ks < 2; ++ks)
      a[m][ks] = *(const bf16x8*)(Pb + (m*16 + fr) * 64 + ks*32 + fq*8);

  const int sw = sc * 512 + w * 128;
  f32x4 acc[8][4] = {};   // [n][m]
#pragma unroll
  for (int n = 0; n < 8; ++n) {
    const u16* vp = Vb + (size_t)(sw + n*16 + fr) * 64 + fq*8;
    const bf16x8 b0 = *(const bf16x8*)(vp);
    const bf16x8 b1 = *(const bf16x8*)(vp + 32);
#pragma unroll
    for (int m = 0; m < 4; ++m)
      acc[n][m] = __builtin_amdgcn_mfma_f32_16x16x32_bf16(a[m][0], b0, acc[n][m], 0, 0, 0);
#pragma unroll
    for (int m = 0; m < 4; ++m)
      acc[n][m] = __builtin_amdgcn_mfma_f32_16x16x32_bf16(a[m][1], b1, acc[n][m], 0, 0, 0);
  }

  const int shi = sc >> 1;
  const int col0 = (sc & 1) * 512 + w * 128;
#pragma unroll
  for (int m = 0; m < 4; ++m)
#pragma unroll
    for (int j = 0; j < 4; ++j) {
      const int d = m*16 + fq*4 + j;
      const size_t base = ((size_t)b * 4096 + (d << 6) + (h << 2) + shi) * 1024 + col0;
#pragma unroll
      for (int n = 0; n < 8; ++n)
        ar[base + n*16 + fr] = f2bf(acc[n][m][j]);
    }
}

// ---------------------------------------------------------------------------
extern "C" void kernel_launch(void* const* d_in, const int* in_sizes, int n_in,
                              void* d_out, int out_size, void* d_ws, size_t ws_size,
                              hipStream_t stream)
{
  const float* x     = (const float*)d_in[0];
  const float* scale = (const float*)d_in[1];
  const float* qw = (const float*)d_in[2];
  const float* qb = (const float*)d_in[3];
  const float* kw = (const float*)d_in[4];
  const float* kb = (const float*)d_in[5];
  const float* vw = (const float*)d_in[6];
  const float* vb = (const float*)d_in[7];
  const float* ow = (const float*)d_in[8];
  const float* ob = (const float*)d_in[9];
  const float* f1w = (const float*)d_in[10];
  const float* f1b = (const float*)d_in[11];
  const float* f2w = (const float*)d_in[12];
  const float* f2b = (const float*)d_in[13];
  float* out = (float*)d_out;

  const size_t TOKD = (size_t)TOKENS * D_MODEL;
  const size_t WSZ1 = (size_t)D_MODEL * D_MODEL;
  const size_t WSZ2 = (size_t)FF_DIM * D_MODEL;
  u16* xn = (u16*)d_ws;
  u16* qt = xn + TOKD;
  u16* kt = qt + TOKD;
  u16* v2 = kt + TOKD;
  u16* wq = v2 + TOKD;        // wq,wk,wv contiguous = concat [3072][1024]
  u16* wk = wq + WSZ1;
  u16* wv = wk + WSZ1;
  u16* wo = wv + WSZ1;
  u16* w1 = wo + WSZ1;
  u16* w2 = w1 + WSZ2;
  u16* Patt = w2 + WSZ2;
  u16* hbuf = kt;             // overlays kt+v2 (dead after attention)
  u16* ar = qt;               // overlays qt (dead after att_sm)

  dim3 blk(256);
  dim3 blk8(512);

  // 0. weights f32 -> bf16
  cvt6_k<<<8192, blk, 0, stream>>>(qw, kw, vw, ow, f1w, f2w, wq, wk, wv, wo, w1, w2);
  // 1. rmsnorm(x) -> xn
  rmsnorm_k<<<TOKENS, blk, 0, stream>>>(x, scale, xn);
  // 2. QKV (merged N=3072): qt/kt [bh][d][s], v2 [bh][s][d]
  g8k<0><<<dim3(TOKENS / 256, 12), blk8, 0, stream>>>(
      xn, wq, qb, kb, vb, nullptr, qt, kt, v2, 3072, D_MODEL);
  // 3. scores + softmax -> Patt
  att_sm_k<<<64, blk, 0, stream>>>(qt, kt, Patt);
  // 4. PV -> ar
  pv2_k<<<dim3(64, 8), blk, 0, stream>>>(Patt, v2, ar);
  // 5. O projection + bias + residual(x) -> out (f32)
  g8k<2><<<dim3(TOKENS / 256, D_MODEL / 256), blk8, 0, stream>>>(
      ar, wo, ob, nullptr, nullptr, x, out, nullptr, nullptr, D_MODEL, D_MODEL);
  // 6. rmsnorm(out) -> xn
  rmsnorm_k<<<TOKENS, blk, 0, stream>>>(out, scale, xn);
  // 7. FFN up + swiglu -> hbuf
  g8k<3><<<dim3(TOKENS / 256, FF_DIM / 256), blk8, 0, stream>>>(
      xn, w1, f1b, nullptr, nullptr, nullptr, hbuf, nullptr, nullptr, FF_DIM, D_MODEL);
  // 8. FFN down + bias + residual(out) -> out
  g8k<2><<<dim3(TOKENS / 256, D_MODEL / 256), blk8, 0, stream>>>(
      hbuf, w2, f2b, nullptr, nullptr, out, out, nullptr, nullptr, D_MODEL, FF_DIM);
}